// Round 1
// baseline (1042.674 us; speedup 1.0000x reference)
//
#include <hip/hip_runtime.h>
#include <stdint.h>

#define NW   1024
#define D    768
#define NS   8192
#define MAXW 30
#define FFNN 1000
#define FEAT 20

// ws layout (in floats)
#define O_P    0                          // 3 * 1024 * 1000  (P1,P2,P3)
#define O_P4   (3*1024*1000)              // 30 * 1000
#define O_HS   (O_P4 + 30*1000)           // 1024
#define O_ATT  (O_HS + 1024)              // 8192 * 32 (stride 32)
#define O_H1   (O_ATT + 8192*32)          // 8192 * 1000
#define O_H2   (O_H1 + 8192*1000)         // 8192 * 1000
#define O_ORD  (O_H2 + 8192*1000)         // 8192 ints

// ---------- head scores: hs[w] = doc[w,:] . w_head + b_head ----------
__global__ __launch_bounds__(256) void k_head(const float* __restrict__ doc,
                                              const float* __restrict__ wh,
                                              const float* __restrict__ bh,
                                              float* __restrict__ hs) {
    int wid = threadIdx.x >> 6, lane = threadIdx.x & 63;
    int word = blockIdx.x * 4 + wid;
    const float* row = doc + word * D;
    float acc = 0.f;
    for (int d = lane; d < D; d += 64) acc += row[d] * wh[d];
    #pragma unroll
    for (int o = 32; o; o >>= 1) acc += __shfl_down(acc, o);
    if (lane == 0) hs[word] = acc + bh[0];
}

// ---------- P4 = w_width_emb @ W1[1536:1556,:] ----------
__global__ __launch_bounds__(256) void k_p4(const float* __restrict__ wwe,
                                            const float* __restrict__ W1,
                                            float* __restrict__ P4) {
    int o = blockIdx.x * 256 + threadIdx.x;
    if (o >= 30 * FFNN) return;
    int wi = o / FFNN, j = o - wi * FFNN;
    float acc = 0.f;
    #pragma unroll
    for (int f = 0; f < FEAT; ++f) acc += wwe[wi * FEAT + f] * W1[(1536 + f) * FFNN + j];
    P4[o] = acc;
}

// ---------- generic fp32 tiled GEMM: C = A(MxK) @ B(KxN) [+bias][relu] ----------
template<bool RELU>
__global__ __launch_bounds__(256) void k_gemm(const float* __restrict__ A,
                                              const float* __restrict__ B,
                                              float* __restrict__ C,
                                              const float* __restrict__ bias,
                                              int M, int N, int K) {
    __shared__ __align__(16) float As[8][68];
    __shared__ __align__(16) float Bs[8][68];
    int tid = threadIdx.x;
    int tx = tid & 15, ty = tid >> 4;
    int row0 = blockIdx.y * 64, col0 = blockIdx.x * 64;
    float acc[4][4] = {};
    for (int kt = 0; kt < K; kt += 8) {
        {   // A tile (64 x 8), transposed into As[k][m]
            int m_l = tid >> 3, k_l = tid & 7;
            As[k_l][m_l]      = A[(row0 + m_l) * K + kt + k_l];
            As[k_l][m_l + 32] = A[(row0 + m_l + 32) * K + kt + k_l];
        }
        {   // B tile (8 x 64)
            int n_l = tid & 63, k_l = tid >> 6;
            int col = col0 + n_l;
            Bs[k_l][n_l]     = (col < N) ? B[(kt + k_l) * N + col] : 0.f;
            Bs[k_l + 4][n_l] = (col < N) ? B[(kt + k_l + 4) * N + col] : 0.f;
        }
        __syncthreads();
        #pragma unroll
        for (int k = 0; k < 8; ++k) {
            float4 a = *(const float4*)&As[k][ty * 4];
            float4 b = *(const float4*)&Bs[k][tx * 4];
            float av[4] = {a.x, a.y, a.z, a.w};
            float bv[4] = {b.x, b.y, b.z, b.w};
            #pragma unroll
            for (int i = 0; i < 4; ++i)
                #pragma unroll
                for (int j = 0; j < 4; ++j)
                    acc[i][j] = fmaf(av[i], bv[j], acc[i][j]);
        }
        __syncthreads();
    }
    #pragma unroll
    for (int i = 0; i < 4; ++i) {
        int row = row0 + ty * 4 + i;
        #pragma unroll
        for (int j = 0; j < 4; ++j) {
            int col = col0 + tx * 4 + j;
            if (col < N) {
                float v = acc[i][j] + (bias ? bias[col] : 0.f);
                if (RELU) v = fmaxf(v, 0.f);
                C[row * N + col] = v;
            }
        }
    }
}

// ---------- attention weights per span ----------
__global__ __launch_bounds__(256) void k_attn(const float* __restrict__ hs,
                                              const int* __restrict__ starts,
                                              const int* __restrict__ ends,
                                              float* __restrict__ attn) {
    int s = blockIdx.x * 256 + threadIdx.x;
    if (s >= NS) return;
    int st = starts[s], en = ends[s];
    int width = en - st + 1;
    float v[MAXW];
    float mx = -3.0e38f;
    #pragma unroll
    for (int w = 0; w < MAXW; ++w) {
        int idx = st + w; if (idx > NW - 1) idx = NW - 1;
        float x = hs[idx];
        v[w] = (w < width) ? x : -3.0e38f;
        mx = fmaxf(mx, v[w]);
    }
    float sum = 0.f;
    #pragma unroll
    for (int w = 0; w < MAXW; ++w) { v[w] = expf(v[w] - mx); sum += v[w]; }
    float inv = 1.f / sum;
    #pragma unroll
    for (int w = 0; w < MAXW; ++w) attn[s * 32 + w] = v[w] * inv;
}

// ---------- h1 assembly: gather P rows + attended + bias + relu ----------
__global__ __launch_bounds__(256) void k_h1(const float* __restrict__ P,
                                            const float* __restrict__ P4,
                                            const float* __restrict__ attn,
                                            const float* __restrict__ b1,
                                            const int* __restrict__ starts,
                                            const int* __restrict__ ends,
                                            float* __restrict__ h1) {
    int s = blockIdx.x;
    int st = starts[s], en = ends[s];
    int width = en - st + 1;
    const float* P1r = P + st * FFNN;
    const float* P2r = P + 1024 * 1000 + en * FFNN;
    const float* P3  = P + 2 * 1024 * 1000;
    const float* P4r = P4 + (width - 1) * FFNN;
    const float* ar  = attn + s * 32;
    float acc[4];
    #pragma unroll
    for (int t = 0; t < 4; ++t) {
        int j = threadIdx.x + t * 256;
        acc[t] = (j < FFNN) ? (P1r[j] + P2r[j] + P4r[j] + b1[j]) : 0.f;
    }
    for (int w = 0; w < width; ++w) {
        float aw = ar[w];
        const float* P3r = P3 + (st + w) * FFNN;
        #pragma unroll
        for (int t = 0; t < 4; ++t) {
            int j = threadIdx.x + t * 256;
            if (j < FFNN) acc[t] += aw * P3r[j];
        }
    }
    #pragma unroll
    for (int t = 0; t < 4; ++t) {
        int j = threadIdx.x + t * 256;
        if (j < FFNN) h1[s * FFNN + j] = fmaxf(acc[t], 0.f);
    }
}

// ---------- final score: h2 . W3 + b3 ----------
__global__ __launch_bounds__(256) void k_score(const float* __restrict__ h2,
                                               const float* __restrict__ W3,
                                               const float* __restrict__ b3,
                                               float* __restrict__ out) {
    int wid = threadIdx.x >> 6, lane = threadIdx.x & 63;
    int s = blockIdx.x * 4 + wid;
    const float* row = h2 + s * FFNN;
    float acc = 0.f;
    for (int i = lane; i < FFNN; i += 64) acc += row[i] * W3[i];
    #pragma unroll
    for (int o = 32; o; o >>= 1) acc += __shfl_down(acc, o);
    if (lane == 0) out[s] = acc + b3[0];
}

// ---------- exact descending argsort via pairwise rank (unique 64-bit keys) ----------
__global__ __launch_bounds__(256) void k_rank(const float* __restrict__ scores,
                                              int* __restrict__ order) {
    __shared__ unsigned long long tile[256];
    int i = blockIdx.x * 256 + threadIdx.x;
    unsigned u = __float_as_uint(scores[i]);
    unsigned m = (u >> 31) ? ~u : (u | 0x80000000u);
    unsigned long long key = ((unsigned long long)(~m) << 32) | (unsigned)i;
    int rank = 0;
    for (int t = 0; t < NS / 256; ++t) {
        int j = t * 256 + threadIdx.x;
        unsigned uj = __float_as_uint(scores[j]);
        unsigned mj = (uj >> 31) ? ~uj : (uj | 0x80000000u);
        tile[threadIdx.x] = ((unsigned long long)(~mj) << 32) | (unsigned)j;
        __syncthreads();
        #pragma unroll 8
        for (int q = 0; q < 256; ++q) rank += (tile[q] < key);
        __syncthreads();
    }
    order[rank] = i;   // order[r] = span index with rank r (descending score)
}

// ---------- sequential greedy crossing-suppression scan (single wave) ----------
__global__ __launch_bounds__(64) void k_scan(const int* __restrict__ order,
                                             const int* __restrict__ starts,
                                             const int* __restrict__ ends,
                                             int top, float* __restrict__ out_idx) {
    __shared__ int max_end[NW];
    __shared__ int min_start[NW];
    __shared__ int sel[1024];
    __shared__ int selkey[1024];
    int lane = threadIdx.x;
    for (int p = lane; p < NW; p += 64) { max_end[p] = -1; min_start[p] = NW; }
    for (int r = lane; r < top; r += 64) sel[r] = -1;
    __syncthreads();
    int count = 0;
    for (int c = 0; c < NS / 64 && count < top; ++c) {
        int span = order[c * 64 + lane];
        int s = starts[span], e = ends[span];
        int w = e - s;                       // width-1
        bool cr = false;
        for (int k = 0; k < w; ++k)
            cr = cr || (max_end[s + 1 + k] > e) || (min_start[s + k] < s);
        // stale-cross is monotone-true -> only !cr spans can ever be accepted.
        unsigned long long mask = __ballot(!cr);
        while (mask) {
            if (count >= top) break;
            int i = __builtin_ctzll(mask);
            mask &= mask - 1;
            int si = __shfl(s, i), ei = __shfl(e, i), spi = __shfl(span, i);
            bool c2 = false;
            if (lane < ei - si)
                c2 = (max_end[si + 1 + lane] > ei) || (min_start[si + lane] < si);
            bool dup2 = (max_end[si] == ei);
            unsigned long long bad = __ballot(c2);
            if (!dup2 && bad == 0ULL) {
                if (lane == 0) {
                    max_end[si]   = max(max_end[si], ei);
                    min_start[ei] = min(min_start[ei], si);
                    sel[count] = spi;
                }
                count++;
            }
            __syncthreads();
        }
        __syncthreads();
    }
    // stable sort of sel[0..top) by key = start*NW + end ( -1 -> big, to back )
    for (int r = lane; r < top; r += 64) {
        int sp = sel[r];
        selkey[r] = (sp >= 0) ? (starts[sp] * NW + ends[sp]) : (NW * NW);
    }
    __syncthreads();
    for (int r = lane; r < top; r += 64) {
        int kr = selkey[r];
        int rank = 0;
        for (int q = 0; q < top; ++q) {
            int kq = selkey[q];
            rank += (kq < kr) || (kq == kr && q < r);
        }
        out_idx[rank] = (float)sel[r];
    }
}

extern "C" void kernel_launch(void* const* d_in, const int* in_sizes, int n_in,
                              void* d_out, int out_size, void* d_ws, size_t ws_size,
                              hipStream_t stream) {
    const float* doc = (const float*)d_in[0];
    const float* wwe = (const float*)d_in[1];
    const float* wh  = (const float*)d_in[2];
    const float* bh  = (const float*)d_in[3];
    const float* W1  = (const float*)d_in[4];
    const float* b1  = (const float*)d_in[5];
    const float* W2  = (const float*)d_in[6];
    const float* b2  = (const float*)d_in[7];
    const float* W3  = (const float*)d_in[8];
    const float* b3  = (const float*)d_in[9];
    const int* starts = (const int*)d_in[10];
    const int* ends   = (const int*)d_in[11];
    int top = out_size - NS;                 // 409

    float* ws  = (float*)d_ws;
    float* P   = ws + O_P;
    float* P4  = ws + O_P4;
    float* HS  = ws + O_HS;
    float* ATT = ws + O_ATT;
    float* H1  = ws + O_H1;
    float* H2  = ws + O_H2;
    int*   ORD = (int*)(ws + O_ORD);
    float* outs = (float*)d_out;

    k_head<<<NW / 4, 256, 0, stream>>>(doc, wh, bh, HS);
    k_p4<<<(30 * FFNN + 255) / 256, 256, 0, stream>>>(wwe, W1, P4);

    dim3 g1((FFNN + 63) / 64, NW / 64);
    k_gemm<false><<<g1, 256, 0, stream>>>(doc, W1,              P,               nullptr, NW, FFNN, D);
    k_gemm<false><<<g1, 256, 0, stream>>>(doc, W1 + 768 * FFNN, P + 1024 * 1000, nullptr, NW, FFNN, D);
    k_gemm<false><<<g1, 256, 0, stream>>>(doc, W1 + 1556 * FFNN, P + 2 * 1024 * 1000, nullptr, NW, FFNN, D);

    k_attn<<<NS / 256, 256, 0, stream>>>(HS, starts, ends, ATT);
    k_h1<<<NS, 256, 0, stream>>>(P, P4, ATT, b1, starts, ends, H1);

    dim3 g2((FFNN + 63) / 64, NS / 64);
    k_gemm<true><<<g2, 256, 0, stream>>>(H1, W2, H2, b2, NS, FFNN, FFNN);

    k_score<<<NS / 4, 256, 0, stream>>>(H2, W3, b3, outs);
    k_rank<<<NS / 256, 256, 0, stream>>>(outs, ORD);
    k_scan<<<1, 64, 0, stream>>>(ORD, starts, ends, top, outs + NS);
}

// Round 2
// 719.065 us; speedup vs baseline: 1.4500x; 1.4500x over previous
//
#include <hip/hip_runtime.h>
#include <stdint.h>

#define NW   1024
#define D    768
#define NS   8192
#define MAXW 30
#define FFNN 1000
#define FEAT 20

// ws layout (in floats)
#define O_P    0                          // 3 * 1024 * 1000  (P1,P2,P3)
#define O_P4   (3*1024*1000)              // 30 * 1000
#define O_HS   (O_P4 + 30*1000)           // 1024
#define O_ATT  (O_HS + 1024)              // 8192 * 32
#define O_H1   (O_ATT + 8192*32)          // 8192 * 1000
#define O_PS   (O_H1 + 8192*1000)         // 8192 * 16 partial scores
#define O_ORD  (O_PS + 8192*16)           // 8192 ints

// ---------- head scores: hs[w] = doc[w,:] . w_head + b_head ----------
__global__ __launch_bounds__(256) void k_head(const float* __restrict__ doc,
                                              const float* __restrict__ wh,
                                              const float* __restrict__ bh,
                                              float* __restrict__ hs) {
    int wid = threadIdx.x >> 6, lane = threadIdx.x & 63;
    int word = blockIdx.x * 4 + wid;
    const float* row = doc + word * D;
    float acc = 0.f;
    for (int d = lane; d < D; d += 64) acc += row[d] * wh[d];
    #pragma unroll
    for (int o = 32; o; o >>= 1) acc += __shfl_down(acc, o);
    if (lane == 0) hs[word] = acc + bh[0];
}

// ---------- P4 = w_width_emb @ W1[1536:1556,:] ----------
__global__ __launch_bounds__(256) void k_p4(const float* __restrict__ wwe,
                                            const float* __restrict__ W1,
                                            float* __restrict__ P4) {
    int o = blockIdx.x * 256 + threadIdx.x;
    if (o >= 30 * FFNN) return;
    int wi = o / FFNN, j = o - wi * FFNN;
    float acc = 0.f;
    #pragma unroll
    for (int f = 0; f < FEAT; ++f) acc += wwe[wi * FEAT + f] * W1[(1536 + f) * FFNN + j];
    P4[o] = acc;
}

// ---------- P GEMM: P[z] = doc @ W1[roff(z):roff(z)+768, :]  (128x64 tile) ----------
__global__ __launch_bounds__(256) void k_gemmP(const float* __restrict__ doc,
                                               const float* __restrict__ W1,
                                               float* __restrict__ Pout) {
    __shared__ __align__(16) float As[8][132];
    __shared__ __align__(16) float Bs[8][68];
    int z = blockIdx.z;
    int roff = (z == 0) ? 0 : (z == 1) ? 768 : 1556;
    const float* A = doc;
    const float* B = W1 + roff * FFNN;
    float* C = Pout + z * NW * FFNN;
    const int K = D;
    int tid = threadIdx.x;
    int row0 = blockIdx.y * 128, col0 = blockIdx.x * 64;
    int arow = tid >> 1, ah = (tid & 1) * 4;
    int bn = tid & 63, bk = tid >> 6;
    int tx = tid & 15, ty = tid >> 4;
    bool bvalid = (col0 + bn) < FFNN;
    int colb = col0 + bn;
    float acc[8][4] = {};
    float4 av = *(const float4*)&A[(row0 + arow) * K + ah];
    float b0 = bvalid ? B[bk * FFNN + colb] : 0.f;
    float b1 = bvalid ? B[(bk + 4) * FFNN + colb] : 0.f;
    for (int kt = 0; kt < K; kt += 8) {
        As[ah + 0][arow] = av.x;
        As[ah + 1][arow] = av.y;
        As[ah + 2][arow] = av.z;
        As[ah + 3][arow] = av.w;
        Bs[bk][bn] = b0;
        Bs[bk + 4][bn] = b1;
        __syncthreads();
        float4 avn = {};
        float b0n = 0.f, b1n = 0.f;
        int kn = kt + 8;
        if (kn < K) {
            avn = *(const float4*)&A[(row0 + arow) * K + kn + ah];
            b0n = bvalid ? B[(kn + bk) * FFNN + colb] : 0.f;
            b1n = bvalid ? B[(kn + bk + 4) * FFNN + colb] : 0.f;
        }
        #pragma unroll
        for (int k = 0; k < 8; ++k) {
            float4 a0 = *(const float4*)&As[k][ty * 8];
            float4 a1 = *(const float4*)&As[k][ty * 8 + 4];
            float4 bv = *(const float4*)&Bs[k][tx * 4];
            float avr[8] = {a0.x, a0.y, a0.z, a0.w, a1.x, a1.y, a1.z, a1.w};
            float bvr[4] = {bv.x, bv.y, bv.z, bv.w};
            #pragma unroll
            for (int i = 0; i < 8; ++i)
                #pragma unroll
                for (int j = 0; j < 4; ++j)
                    acc[i][j] = fmaf(avr[i], bvr[j], acc[i][j]);
        }
        __syncthreads();
        av = avn; b0 = b0n; b1 = b1n;
    }
    #pragma unroll
    for (int i = 0; i < 8; ++i) {
        int row = row0 + ty * 8 + i;
        #pragma unroll
        for (int j = 0; j < 4; ++j) {
            int col = col0 + tx * 4 + j;
            if (col < FFNN) C[row * FFNN + col] = acc[i][j];
        }
    }
}

// ---------- GEMM2 fused: relu(H1@W2+b2) dotted with W3 -> partial scores ----------
__global__ __launch_bounds__(256) void k_gemm2(const float* __restrict__ A,   // H1 8192x1000
                                               const float* __restrict__ B,   // W2 1000x1000
                                               const float* __restrict__ bias,// b2
                                               const float* __restrict__ W3,
                                               float* __restrict__ PS) {      // 8192x16
    __shared__ __align__(16) float As[8][132];
    __shared__ __align__(16) float Bs[8][68];
    const int K = FFNN;
    int tid = threadIdx.x;
    int row0 = blockIdx.y * 128, col0 = blockIdx.x * 64;
    int arow = tid >> 1, ah = (tid & 1) * 4;
    int bn = tid & 63, bk = tid >> 6;
    int tx = tid & 15, ty = tid >> 4;
    bool bvalid = (col0 + bn) < FFNN;
    int colb = col0 + bn;
    float acc[8][4] = {};
    float4 av = *(const float4*)&A[(row0 + arow) * K + ah];
    float b0 = bvalid ? B[bk * FFNN + colb] : 0.f;
    float b1 = bvalid ? B[(bk + 4) * FFNN + colb] : 0.f;
    for (int kt = 0; kt < K; kt += 8) {
        As[ah + 0][arow] = av.x;
        As[ah + 1][arow] = av.y;
        As[ah + 2][arow] = av.z;
        As[ah + 3][arow] = av.w;
        Bs[bk][bn] = b0;
        Bs[bk + 4][bn] = b1;
        __syncthreads();
        float4 avn = {};
        float b0n = 0.f, b1n = 0.f;
        int kn = kt + 8;
        if (kn < K) {
            avn = *(const float4*)&A[(row0 + arow) * K + kn + ah];
            b0n = bvalid ? B[(kn + bk) * FFNN + colb] : 0.f;
            b1n = bvalid ? B[(kn + bk + 4) * FFNN + colb] : 0.f;
        }
        #pragma unroll
        for (int k = 0; k < 8; ++k) {
            float4 a0 = *(const float4*)&As[k][ty * 8];
            float4 a1 = *(const float4*)&As[k][ty * 8 + 4];
            float4 bv = *(const float4*)&Bs[k][tx * 4];
            float avr[8] = {a0.x, a0.y, a0.z, a0.w, a1.x, a1.y, a1.z, a1.w};
            float bvr[4] = {bv.x, bv.y, bv.z, bv.w};
            #pragma unroll
            for (int i = 0; i < 8; ++i)
                #pragma unroll
                for (int j = 0; j < 4; ++j)
                    acc[i][j] = fmaf(avr[i], bvr[j], acc[i][j]);
        }
        __syncthreads();
        av = avn; b0 = b0n; b1 = b1n;
    }
    // epilogue: relu(acc + b2) . W3 -> per-row partial, reduce over 16 tx lanes
    float w3v[4], b2v[4];
    #pragma unroll
    for (int j = 0; j < 4; ++j) {
        int col = col0 + tx * 4 + j;
        w3v[j] = (col < FFNN) ? W3[col] : 0.f;
        b2v[j] = (col < FFNN) ? bias[col] : 0.f;
    }
    #pragma unroll
    for (int i = 0; i < 8; ++i) {
        float p = 0.f;
        #pragma unroll
        for (int j = 0; j < 4; ++j) {
            float v = fmaxf(acc[i][j] + b2v[j], 0.f);
            p += v * w3v[j];
        }
        #pragma unroll
        for (int o = 8; o; o >>= 1) p += __shfl_down(p, o, 16);
        if (tx == 0) {
            int row = row0 + ty * 8 + i;
            PS[row * 16 + blockIdx.x] = p;
        }
    }
}

// ---------- attention weights per span ----------
__global__ __launch_bounds__(256) void k_attn(const float* __restrict__ hs,
                                              const int* __restrict__ starts,
                                              const int* __restrict__ ends,
                                              float* __restrict__ attn) {
    int s = blockIdx.x * 256 + threadIdx.x;
    if (s >= NS) return;
    int st = starts[s], en = ends[s];
    int width = en - st + 1;
    float v[MAXW];
    float mx = -3.0e38f;
    #pragma unroll
    for (int w = 0; w < MAXW; ++w) {
        int idx = st + w; if (idx > NW - 1) idx = NW - 1;
        float x = hs[idx];
        v[w] = (w < width) ? x : -3.0e38f;
        mx = fmaxf(mx, v[w]);
    }
    float sum = 0.f;
    #pragma unroll
    for (int w = 0; w < MAXW; ++w) { v[w] = expf(v[w] - mx); sum += v[w]; }
    float inv = 1.f / sum;
    #pragma unroll
    for (int w = 0; w < MAXW; ++w) attn[s * 32 + w] = v[w] * inv;
}

// ---------- h1 assembly (float4): gather P rows + attended + bias + relu ----------
__global__ __launch_bounds__(256) void k_h1(const float* __restrict__ P,
                                            const float* __restrict__ P4,
                                            const float* __restrict__ attn,
                                            const float* __restrict__ b1,
                                            const int* __restrict__ starts,
                                            const int* __restrict__ ends,
                                            float* __restrict__ h1) {
    int s = blockIdx.x;
    int tid = threadIdx.x;
    if (tid >= 250) return;
    int st = starts[s], en = ends[s];
    int width = en - st + 1;
    const float4* P1r = (const float4*)(P + st * FFNN);
    const float4* P2r = (const float4*)(P + NW * FFNN + en * FFNN);
    const float*  P3  = P + 2 * NW * FFNN;
    const float4* P4r = (const float4*)(P4 + (width - 1) * FFNN);
    const float4* b1v = (const float4*)b1;
    const float*  ar  = attn + s * 32;
    float4 a = P1r[tid], b = P2r[tid], c = P4r[tid], d = b1v[tid];
    float4 acc = {a.x + b.x + c.x + d.x,
                  a.y + b.y + c.y + d.y,
                  a.z + b.z + c.z + d.z,
                  a.w + b.w + c.w + d.w};
    for (int w = 0; w < width; ++w) {
        float aw = ar[w];
        float4 p3 = ((const float4*)(P3 + (st + w) * FFNN))[tid];
        acc.x = fmaf(aw, p3.x, acc.x);
        acc.y = fmaf(aw, p3.y, acc.y);
        acc.z = fmaf(aw, p3.z, acc.z);
        acc.w = fmaf(aw, p3.w, acc.w);
    }
    float4 r = {fmaxf(acc.x, 0.f), fmaxf(acc.y, 0.f), fmaxf(acc.z, 0.f), fmaxf(acc.w, 0.f)};
    ((float4*)(h1 + s * FFNN))[tid] = r;
}

// ---------- final score: sum 16 partials + b3 (deterministic order) ----------
__global__ __launch_bounds__(256) void k_score2(const float* __restrict__ PS,
                                                const float* __restrict__ b3,
                                                float* __restrict__ out) {
    int r = blockIdx.x * 256 + threadIdx.x;
    if (r >= NS) return;
    float s = 0.f;
    #pragma unroll
    for (int b = 0; b < 16; ++b) s += PS[r * 16 + b];
    out[r] = s + b3[0];
}

// ---------- exact descending argsort via pairwise rank (unique 64-bit keys) ----------
__global__ __launch_bounds__(256) void k_rank(const float* __restrict__ scores,
                                              int* __restrict__ order) {
    __shared__ unsigned long long tile[256];
    int i = blockIdx.x * 256 + threadIdx.x;
    unsigned u = __float_as_uint(scores[i]);
    unsigned m = (u >> 31) ? ~u : (u | 0x80000000u);
    unsigned long long key = ((unsigned long long)(~m) << 32) | (unsigned)i;
    int rank = 0;
    for (int t = 0; t < NS / 256; ++t) {
        int j = t * 256 + threadIdx.x;
        unsigned uj = __float_as_uint(scores[j]);
        unsigned mj = (uj >> 31) ? ~uj : (uj | 0x80000000u);
        tile[threadIdx.x] = ((unsigned long long)(~mj) << 32) | (unsigned)j;
        __syncthreads();
        #pragma unroll 8
        for (int q = 0; q < 256; ++q) rank += (tile[q] < key);
        __syncthreads();
    }
    order[rank] = i;
}

// ---------- sequential greedy crossing-suppression scan (single wave) ----------
__global__ __launch_bounds__(64) void k_scan(const int* __restrict__ order,
                                             const int* __restrict__ starts,
                                             const int* __restrict__ ends,
                                             int top, float* __restrict__ out_idx) {
    __shared__ int max_end[NW];
    __shared__ int min_start[NW];
    __shared__ int sel[512];
    __shared__ int selkey[512];
    int lane = threadIdx.x;
    for (int p = lane; p < NW; p += 64) { max_end[p] = -1; min_start[p] = NW; }
    for (int r = lane; r < top; r += 64) sel[r] = -1;
    __syncthreads();
    int count = 0;
    for (int c = 0; c < NS / 64 && count < top; ++c) {
        int span = order[c * 64 + lane];
        int s = starts[span], e = ends[span];
        int w = e - s;                       // width-1
        int bad = 0;
        for (int k = 0; k < w; ++k)
            bad |= (max_end[s + 1 + k] > e) | (min_start[s + k] < s);
        // stale-cross is monotone-true -> only !bad spans can ever be accepted.
        unsigned long long mask = __ballot(!bad);
        while (mask && count < top) {
            int i = __builtin_ctzll(mask);
            mask &= mask - 1;
            int si = __shfl(s, i), ei = __shfl(e, i), spi = __shfl(span, i);
            int c2 = 0;
            if (lane < ei - si)
                c2 = (max_end[si + 1 + lane] > ei) | (min_start[si + lane] < si);
            bool dup2 = (max_end[si] == ei);
            unsigned long long badm = __ballot(c2 != 0);
            if (!dup2 && badm == 0ULL) {
                if (lane == 0) {
                    max_end[si]   = max(max_end[si], ei);
                    min_start[ei] = min(min_start[ei], si);
                    sel[count] = spi;
                }
                count++;
            }
            __syncthreads();
        }
        __syncthreads();
    }
    // stable sort of sel[0..top) by key = start*NW + end ( -1 -> big, to back )
    for (int r = lane; r < top; r += 64) {
        int sp = sel[r];
        selkey[r] = (sp >= 0) ? (starts[sp] * NW + ends[sp]) : (NW * NW);
    }
    __syncthreads();
    for (int r = lane; r < top; r += 64) {
        int kr = selkey[r];
        int rank = 0;
        for (int q = 0; q < top; ++q) {
            int kq = selkey[q];
            rank += (kq < kr) || (kq == kr && q < r);
        }
        out_idx[rank] = (float)sel[r];
    }
}

extern "C" void kernel_launch(void* const* d_in, const int* in_sizes, int n_in,
                              void* d_out, int out_size, void* d_ws, size_t ws_size,
                              hipStream_t stream) {
    const float* doc = (const float*)d_in[0];
    const float* wwe = (const float*)d_in[1];
    const float* wh  = (const float*)d_in[2];
    const float* bh  = (const float*)d_in[3];
    const float* W1  = (const float*)d_in[4];
    const float* b1  = (const float*)d_in[5];
    const float* W2  = (const float*)d_in[6];
    const float* b2  = (const float*)d_in[7];
    const float* W3  = (const float*)d_in[8];
    const float* b3  = (const float*)d_in[9];
    const int* starts = (const int*)d_in[10];
    const int* ends   = (const int*)d_in[11];
    int top = out_size - NS;                 // 409

    float* ws  = (float*)d_ws;
    float* P   = ws + O_P;
    float* P4  = ws + O_P4;
    float* HS  = ws + O_HS;
    float* ATT = ws + O_ATT;
    float* H1  = ws + O_H1;
    float* PS  = ws + O_PS;
    int*   ORD = (int*)(ws + O_ORD);
    float* outs = (float*)d_out;

    k_head<<<NW / 4, 256, 0, stream>>>(doc, wh, bh, HS);
    k_p4<<<(30 * FFNN + 255) / 256, 256, 0, stream>>>(wwe, W1, P4);

    dim3 g1(16, NW / 128, 3);
    k_gemmP<<<g1, 256, 0, stream>>>(doc, W1, P);

    k_attn<<<NS / 256, 256, 0, stream>>>(HS, starts, ends, ATT);
    k_h1<<<NS, 256, 0, stream>>>(P, P4, ATT, b1, starts, ends, H1);

    dim3 g2(16, NS / 128);
    k_gemm2<<<g2, 256, 0, stream>>>(H1, W2, b2, W3, PS);

    k_score2<<<NS / 256, 256, 0, stream>>>(PS, b3, outs);
    k_rank<<<NS / 256, 256, 0, stream>>>(outs, ORD);
    k_scan<<<1, 64, 0, stream>>>(ORD, starts, ends, top, outs + NS);
}

// Round 3
// 670.515 us; speedup vs baseline: 1.5550x; 1.0724x over previous
//
#include <hip/hip_runtime.h>
#include <stdint.h>

#define NW   1024
#define D    768
#define NS   8192
#define MAXW 30
#define FFNN 1000
#define FEAT 20

// ws layout (in floats)
#define O_P    0                          // 3 * 1024 * 1000  (P1,P2,P3)
#define O_P4   (3*1024*1000)              // 30 * 1000
#define O_HS   (O_P4 + 30*1000)           // 1024
#define O_ATT  (O_HS + 1024)              // 8192 * 32
#define O_H1   (O_ATT + 8192*32)          // 8192 * 1000
#define O_PS   (O_H1 + 8192*1000)         // 8192 * 16 partial scores (8 used)
#define O_ORD  (O_PS + 8192*16)           // 8192 ints

// ---------- head scores: hs[w] = doc[w,:] . w_head + b_head ----------
__global__ __launch_bounds__(256) void k_head(const float* __restrict__ doc,
                                              const float* __restrict__ wh,
                                              const float* __restrict__ bh,
                                              float* __restrict__ hs) {
    int wid = threadIdx.x >> 6, lane = threadIdx.x & 63;
    int word = blockIdx.x * 4 + wid;
    const float* row = doc + word * D;
    float acc = 0.f;
    for (int d = lane; d < D; d += 64) acc += row[d] * wh[d];
    #pragma unroll
    for (int o = 32; o; o >>= 1) acc += __shfl_down(acc, o);
    if (lane == 0) hs[word] = acc + bh[0];
}

// ---------- P4 = w_width_emb @ W1[1536:1556,:] ----------
__global__ __launch_bounds__(256) void k_p4(const float* __restrict__ wwe,
                                            const float* __restrict__ W1,
                                            float* __restrict__ P4) {
    int o = blockIdx.x * 256 + threadIdx.x;
    if (o >= 30 * FFNN) return;
    int wi = o / FFNN, j = o - wi * FFNN;
    float acc = 0.f;
    #pragma unroll
    for (int f = 0; f < FEAT; ++f) acc += wwe[wi * FEAT + f] * W1[(1536 + f) * FFNN + j];
    P4[o] = acc;
}

// ---------- P GEMM: P[z] = doc @ W1[roff(z):roff(z)+768, :]  (128x64 tile) ----------
__global__ __launch_bounds__(256) void k_gemmP(const float* __restrict__ doc,
                                               const float* __restrict__ W1,
                                               float* __restrict__ Pout) {
    __shared__ __align__(16) float As[8][132];
    __shared__ __align__(16) float Bs[8][68];
    int z = blockIdx.z;
    int roff = (z == 0) ? 0 : (z == 1) ? 768 : 1556;
    const float* A = doc;
    const float* B = W1 + roff * FFNN;
    float* C = Pout + z * NW * FFNN;
    const int K = D;
    int tid = threadIdx.x;
    int row0 = blockIdx.y * 128, col0 = blockIdx.x * 64;
    int arow = tid >> 1, ah = (tid & 1) * 4;
    int bn = tid & 63, bk = tid >> 6;
    int tx = tid & 15, ty = tid >> 4;
    bool bvalid = (col0 + bn) < FFNN;
    int colb = col0 + bn;
    float acc[8][4] = {};
    float4 av = *(const float4*)&A[(row0 + arow) * K + ah];
    float b0 = bvalid ? B[bk * FFNN + colb] : 0.f;
    float b1 = bvalid ? B[(bk + 4) * FFNN + colb] : 0.f;
    for (int kt = 0; kt < K; kt += 8) {
        As[ah + 0][arow] = av.x;
        As[ah + 1][arow] = av.y;
        As[ah + 2][arow] = av.z;
        As[ah + 3][arow] = av.w;
        Bs[bk][bn] = b0;
        Bs[bk + 4][bn] = b1;
        __syncthreads();
        float4 avn = {};
        float b0n = 0.f, b1n = 0.f;
        int kn = kt + 8;
        if (kn < K) {
            avn = *(const float4*)&A[(row0 + arow) * K + kn + ah];
            b0n = bvalid ? B[(kn + bk) * FFNN + colb] : 0.f;
            b1n = bvalid ? B[(kn + bk + 4) * FFNN + colb] : 0.f;
        }
        #pragma unroll
        for (int k = 0; k < 8; ++k) {
            float4 a0 = *(const float4*)&As[k][ty * 8];
            float4 a1 = *(const float4*)&As[k][ty * 8 + 4];
            float4 bv = *(const float4*)&Bs[k][tx * 4];
            float avr[8] = {a0.x, a0.y, a0.z, a0.w, a1.x, a1.y, a1.z, a1.w};
            float bvr[4] = {bv.x, bv.y, bv.z, bv.w};
            #pragma unroll
            for (int i = 0; i < 8; ++i)
                #pragma unroll
                for (int j = 0; j < 4; ++j)
                    acc[i][j] = fmaf(avr[i], bvr[j], acc[i][j]);
        }
        __syncthreads();
        av = avn; b0 = b0n; b1 = b1n;
    }
    #pragma unroll
    for (int i = 0; i < 8; ++i) {
        int row = row0 + ty * 8 + i;
        #pragma unroll
        for (int j = 0; j < 4; ++j) {
            int col = col0 + tx * 4 + j;
            if (col < FFNN) C[row * FFNN + col] = acc[i][j];
        }
    }
}

// ---------- GEMM2 fused: relu(H1@W2+b2) dotted with W3 -> partial scores ----------
// 128x128 tile, 8x8 acc per thread
__global__ __launch_bounds__(256) void k_gemm2(const float* __restrict__ A,   // H1 8192x1000
                                               const float* __restrict__ B,   // W2 1000x1000
                                               const float* __restrict__ bias,// b2
                                               const float* __restrict__ W3,
                                               float* __restrict__ PS) {      // 8192x8
    __shared__ __align__(16) float As[8][132];
    __shared__ __align__(16) float Bs[8][132];
    const int K = FFNN;
    int tid = threadIdx.x;
    int row0 = blockIdx.y * 128, col0 = blockIdx.x * 128;
    int arow = tid >> 1, ah = (tid & 1) * 4;      // A: 128 rows x 8 k
    int bcol = (tid & 31) * 4, bk = tid >> 5;     // B: 8 k x 128 cols (float4)
    int tx = tid & 15, ty = tid >> 4;
    int colb = col0 + bcol;
    bool bvalid = (colb + 3) < FFNN;              // FFNN % 4 == 0 -> no straddle
    float acc[8][8] = {};
    float4 av = *(const float4*)&A[(row0 + arow) * K + ah];
    float4 bv = bvalid ? *(const float4*)&B[bk * FFNN + colb] : float4{0.f, 0.f, 0.f, 0.f};
    for (int kt = 0; kt < K; kt += 8) {
        As[ah + 0][arow] = av.x;
        As[ah + 1][arow] = av.y;
        As[ah + 2][arow] = av.z;
        As[ah + 3][arow] = av.w;
        *(float4*)&Bs[bk][bcol] = bv;
        __syncthreads();
        float4 avn = {0.f, 0.f, 0.f, 0.f}, bvn = {0.f, 0.f, 0.f, 0.f};
        int kn = kt + 8;
        if (kn < K) {
            avn = *(const float4*)&A[(row0 + arow) * K + kn + ah];
            bvn = bvalid ? *(const float4*)&B[(kn + bk) * FFNN + colb] : float4{0.f, 0.f, 0.f, 0.f};
        }
        #pragma unroll
        for (int k = 0; k < 8; ++k) {
            float4 a0 = *(const float4*)&As[k][ty * 8];
            float4 a1 = *(const float4*)&As[k][ty * 8 + 4];
            float4 c0 = *(const float4*)&Bs[k][tx * 8];
            float4 c1 = *(const float4*)&Bs[k][tx * 8 + 4];
            float avr[8] = {a0.x, a0.y, a0.z, a0.w, a1.x, a1.y, a1.z, a1.w};
            float bvr[8] = {c0.x, c0.y, c0.z, c0.w, c1.x, c1.y, c1.z, c1.w};
            #pragma unroll
            for (int i = 0; i < 8; ++i)
                #pragma unroll
                for (int j = 0; j < 8; ++j)
                    acc[i][j] = fmaf(avr[i], bvr[j], acc[i][j]);
        }
        __syncthreads();
        av = avn; bv = bvn;
    }
    // epilogue: relu(acc + b2) . W3 -> per-row partial, reduce over 16 tx lanes
    float w3v[8], b2v[8];
    #pragma unroll
    for (int j = 0; j < 8; ++j) {
        int col = col0 + tx * 8 + j;
        w3v[j] = (col < FFNN) ? W3[col] : 0.f;
        b2v[j] = (col < FFNN) ? bias[col] : 0.f;
    }
    #pragma unroll
    for (int i = 0; i < 8; ++i) {
        float p = 0.f;
        #pragma unroll
        for (int j = 0; j < 8; ++j) {
            float v = fmaxf(acc[i][j] + b2v[j], 0.f);
            p = fmaf(v, w3v[j], p);
        }
        #pragma unroll
        for (int o = 8; o; o >>= 1) p += __shfl_down(p, o, 16);
        if (tx == 0) {
            int row = row0 + ty * 8 + i;
            PS[row * 8 + blockIdx.x] = p;
        }
    }
}

// ---------- attention weights per span ----------
__global__ __launch_bounds__(256) void k_attn(const float* __restrict__ hs,
                                              const int* __restrict__ starts,
                                              const int* __restrict__ ends,
                                              float* __restrict__ attn) {
    int s = blockIdx.x * 256 + threadIdx.x;
    if (s >= NS) return;
    int st = starts[s], en = ends[s];
    int width = en - st + 1;
    float v[MAXW];
    float mx = -3.0e38f;
    #pragma unroll
    for (int w = 0; w < MAXW; ++w) {
        int idx = st + w; if (idx > NW - 1) idx = NW - 1;
        float x = hs[idx];
        v[w] = (w < width) ? x : -3.0e38f;
        mx = fmaxf(mx, v[w]);
    }
    float sum = 0.f;
    #pragma unroll
    for (int w = 0; w < MAXW; ++w) { v[w] = expf(v[w] - mx); sum += v[w]; }
    float inv = 1.f / sum;
    #pragma unroll
    for (int w = 0; w < MAXW; ++w) attn[s * 32 + w] = v[w] * inv;
}

// ---------- h1 assembly (float4): gather P rows + attended + bias + relu ----------
__global__ __launch_bounds__(256) void k_h1(const float* __restrict__ P,
                                            const float* __restrict__ P4,
                                            const float* __restrict__ attn,
                                            const float* __restrict__ b1,
                                            const int* __restrict__ starts,
                                            const int* __restrict__ ends,
                                            float* __restrict__ h1) {
    int s = blockIdx.x;
    int tid = threadIdx.x;
    if (tid >= 250) return;
    int st = starts[s], en = ends[s];
    int width = en - st + 1;
    const float4* P1r = (const float4*)(P + st * FFNN);
    const float4* P2r = (const float4*)(P + NW * FFNN + en * FFNN);
    const float*  P3  = P + 2 * NW * FFNN;
    const float4* P4r = (const float4*)(P4 + (width - 1) * FFNN);
    const float4* b1v = (const float4*)b1;
    const float*  ar  = attn + s * 32;
    float4 a = P1r[tid], b = P2r[tid], c = P4r[tid], d = b1v[tid];
    float4 acc = {a.x + b.x + c.x + d.x,
                  a.y + b.y + c.y + d.y,
                  a.z + b.z + c.z + d.z,
                  a.w + b.w + c.w + d.w};
    for (int w = 0; w < width; ++w) {
        float aw = ar[w];
        float4 p3 = ((const float4*)(P3 + (st + w) * FFNN))[tid];
        acc.x = fmaf(aw, p3.x, acc.x);
        acc.y = fmaf(aw, p3.y, acc.y);
        acc.z = fmaf(aw, p3.z, acc.z);
        acc.w = fmaf(aw, p3.w, acc.w);
    }
    float4 r = {fmaxf(acc.x, 0.f), fmaxf(acc.y, 0.f), fmaxf(acc.z, 0.f), fmaxf(acc.w, 0.f)};
    ((float4*)(h1 + s * FFNN))[tid] = r;
}

// ---------- final score: sum 8 partials + b3 (deterministic order) ----------
__global__ __launch_bounds__(256) void k_score2(const float* __restrict__ PS,
                                                const float* __restrict__ b3,
                                                float* __restrict__ out) {
    int r = blockIdx.x * 256 + threadIdx.x;
    if (r >= NS) return;
    float s = 0.f;
    #pragma unroll
    for (int b = 0; b < 8; ++b) s += PS[r * 8 + b];
    out[r] = s + b3[0];
}

// ---------- exact descending argsort via pairwise rank (unique 64-bit keys) ----------
__global__ __launch_bounds__(256) void k_rank(const float* __restrict__ scores,
                                              int* __restrict__ order) {
    __shared__ unsigned long long tile[256];
    int i = blockIdx.x * 256 + threadIdx.x;
    unsigned u = __float_as_uint(scores[i]);
    unsigned m = (u >> 31) ? ~u : (u | 0x80000000u);
    unsigned long long key = ((unsigned long long)(~m) << 32) | (unsigned)i;
    int rank = 0;
    for (int t = 0; t < NS / 256; ++t) {
        int j = t * 256 + threadIdx.x;
        unsigned uj = __float_as_uint(scores[j]);
        unsigned mj = (uj >> 31) ? ~uj : (uj | 0x80000000u);
        tile[threadIdx.x] = ((unsigned long long)(~mj) << 32) | (unsigned)j;
        __syncthreads();
        #pragma unroll 8
        for (int q = 0; q < 256; ++q) rank += (tile[q] < key);
        __syncthreads();
    }
    order[rank] = i;
}

// ---------- greedy crossing-suppression scan: chunk-parallel exact resolution ----------
// Per 64-span chunk: global state is exact at chunk start (updated only between
// chunks). Global cross/dup checked in parallel; in-chunk interactions resolved
// via 64-bit pairwise masks + ballot-only rounds (no per-accept LDS round trip).
__global__ __launch_bounds__(64) void k_scan(const int* __restrict__ order,
                                             const int* __restrict__ starts,
                                             const int* __restrict__ ends,
                                             int top, float* __restrict__ out_idx) {
    __shared__ int max_end[NW];
    __shared__ int min_start[NW];
    __shared__ int sel[512];
    __shared__ int selkey[512];
    int lane = threadIdx.x;
    unsigned long long lower = (1ull << lane) - 1ull;
    for (int p = lane; p < NW; p += 64) { max_end[p] = -1; min_start[p] = NW; }
    for (int r = lane; r < top; r += 64) sel[r] = -1;
    __syncthreads();
    int count = 0;
    // prefetch chunk 0
    int span = order[lane];
    int s = starts[span], e = ends[span];
    for (int c = 0; c < NS / 64; ++c) {
        int nspan = 0, ns = 0, ne = 0;
        if (c + 1 < NS / 64) {                 // prefetch next chunk
            nspan = order[(c + 1) * 64 + lane];
            ns = starts[nspan]; ne = ends[nspan];
        }
        int w = e - s;                          // width-1
        int bad = 0;
        for (int k = 0; k < w; ++k)             // exact global cross check
            bad |= (max_end[s + 1 + k] > e) | (min_start[s + k] < s);
        int g = max_end[s];
        bool gdup = (g == e), ggt = (g > e);
        unsigned long long M = __ballot(!bad);  // in-chunk candidates
        if (M) {
            // pairwise masks vs candidate lanes i (potential in-chunk accepts)
            unsigned long long conf = 0, eqm = 0, gtm = 0;
            unsigned long long t = M;
            while (t) {
                int i = __builtin_ctzll(t); t &= t - 1;
                int si = __builtin_amdgcn_readlane(s, i);
                int ei = __builtin_amdgcn_readlane(e, i);
                unsigned long long bit = 1ull << i;
                // i accepted would cross me (j): start inside (s,e] ending past e,
                // or end inside [s,e) starting before s
                if (((si > s) & (si <= e) & (ei > e)) |
                    ((ei >= s) & (ei < e) & (si < s))) conf |= bit;
                if (si == s) { if (ei == e) eqm |= bit; else if (ei > e) gtm |= bit; }
            }
            // ballot-only sequential-order resolution
            unsigned long long pending = M, committed = 0;
            while (pending) {
                bool mine = (pending >> lane) & 1;
                unsigned long long relv = (conf | eqm | gtm) & lower;
                bool ready = mine && ((pending & relv) == 0ull);
                unsigned long long cb = committed & lower;
                bool rej = (cb & conf) != 0ull;
                bool gt_any = ggt || ((cb & gtm) != 0ull);
                bool eq_any = gdup || ((cb & eqm) != 0ull);
                bool acc_now = ready && !rej && !(eq_any && !gt_any);
                committed |= __ballot(acc_now);
                pending &= ~__ballot(ready);
            }
            // cap at top: keep first (top-count) accepts (exactly equals capped scan)
            int allowed = top - count;
            while (__popcll(committed) > allowed)
                committed &= ~(1ull << (63 - __builtin_clzll(committed)));
            if ((committed >> lane) & 1) {
                atomicMax(&max_end[s], e);
                atomicMin(&min_start[e], s);
                int pos = count + __popcll(committed & lower);
                sel[pos] = span;
            }
            count += __popcll(committed);
        }
        __syncthreads();
        if (count >= top) break;
        span = nspan; s = ns; e = ne;
    }
    // stable sort of sel[0..top) by key = start*NW + end ( -1 -> big, to back )
    for (int r = lane; r < top; r += 64) {
        int sp = sel[r];
        selkey[r] = (sp >= 0) ? (starts[sp] * NW + ends[sp]) : (NW * NW);
    }
    __syncthreads();
    for (int r = lane; r < top; r += 64) {
        int kr = selkey[r];
        int rank = 0;
        for (int q = 0; q < top; ++q) {
            int kq = selkey[q];
            rank += (kq < kr) || (kq == kr && q < r);
        }
        out_idx[rank] = (float)sel[r];
    }
}

extern "C" void kernel_launch(void* const* d_in, const int* in_sizes, int n_in,
                              void* d_out, int out_size, void* d_ws, size_t ws_size,
                              hipStream_t stream) {
    const float* doc = (const float*)d_in[0];
    const float* wwe = (const float*)d_in[1];
    const float* wh  = (const float*)d_in[2];
    const float* bh  = (const float*)d_in[3];
    const float* W1  = (const float*)d_in[4];
    const float* b1  = (const float*)d_in[5];
    const float* W2  = (const float*)d_in[6];
    const float* b2  = (const float*)d_in[7];
    const float* W3  = (const float*)d_in[8];
    const float* b3  = (const float*)d_in[9];
    const int* starts = (const int*)d_in[10];
    const int* ends   = (const int*)d_in[11];
    int top = out_size - NS;                 // 409

    float* ws  = (float*)d_ws;
    float* P   = ws + O_P;
    float* P4  = ws + O_P4;
    float* HS  = ws + O_HS;
    float* ATT = ws + O_ATT;
    float* H1  = ws + O_H1;
    float* PS  = ws + O_PS;
    int*   ORD = (int*)(ws + O_ORD);
    float* outs = (float*)d_out;

    k_head<<<NW / 4, 256, 0, stream>>>(doc, wh, bh, HS);
    k_p4<<<(30 * FFNN + 255) / 256, 256, 0, stream>>>(wwe, W1, P4);

    dim3 g1(16, NW / 128, 3);
    k_gemmP<<<g1, 256, 0, stream>>>(doc, W1, P);

    k_attn<<<NS / 256, 256, 0, stream>>>(HS, starts, ends, ATT);
    k_h1<<<NS, 256, 0, stream>>>(P, P4, ATT, b1, starts, ends, H1);

    dim3 g2(8, NS / 128);
    k_gemm2<<<g2, 256, 0, stream>>>(H1, W2, b2, W3, PS);

    k_score2<<<NS / 256, 256, 0, stream>>>(PS, b3, outs);
    k_rank<<<NS / 256, 256, 0, stream>>>(outs, ORD);
    k_scan<<<1, 64, 0, stream>>>(ORD, starts, ends, top, outs + NS);
}

// Round 4
// 523.312 us; speedup vs baseline: 1.9924x; 1.2813x over previous
//
#include <hip/hip_runtime.h>
#include <hip/hip_bf16.h>
#include <stdint.h>

#define NW   1024
#define D    768
#define NS   8192
#define MAXW 30
#define FFNN 1000
#define FEAT 20

typedef __attribute__((ext_vector_type(8))) short bf16x8;
typedef __attribute__((ext_vector_type(4))) float f32x4;
#define MFMA16 __builtin_amdgcn_mfma_f32_16x16x32_bf16

// ws layout (float-slot offsets) — total 11,696,432 floats = 46.78 MB (== R1 proven)
#define O_P    0                          // 3*1024*1000 fp32 P1,P2,P3
#define O_P4   3072000                    // 30*1000
#define O_HS   3102000                    // 1024
#define O_ATT  3103024                    // 8192*32
#define O_PS   3365168                    // 8192*16
#define O_ORD  3496240                    // 8192 ints
#define O_H1R  3504432                    // 8,192,000 fl region: H1 hi/lo bf16
// aliases inside H1 region (dead before k_h1 writes):
//   W1TH @ +0 (1,179,648 fl), W1TL @ +1,179,648, DOCH @ +2,359,296, DOCL @ +2,752,512
// alias over P region (after k_h1): W2TH @ 0 (512,000 fl), W2TL @ 512,000

__device__ inline ushort f2b(float v) {
    __hip_bfloat16 b = __float2bfloat16(v);
    return *(ushort*)&b;
}
__device__ inline float b2f(ushort u) {
    __hip_bfloat16 b = *(__hip_bfloat16*)&u;
    return __bfloat162float(b);
}

// ---------- head scores ----------
__global__ __launch_bounds__(256) void k_head(const float* __restrict__ doc,
                                              const float* __restrict__ wh,
                                              const float* __restrict__ bh,
                                              float* __restrict__ hs) {
    int wid = threadIdx.x >> 6, lane = threadIdx.x & 63;
    int word = blockIdx.x * 4 + wid;
    const float* row = doc + word * D;
    float acc = 0.f;
    for (int d = lane; d < D; d += 64) acc += row[d] * wh[d];
    #pragma unroll
    for (int o = 32; o; o >>= 1) acc += __shfl_down(acc, o);
    if (lane == 0) hs[word] = acc + bh[0];
}

// ---------- P4 = w_width_emb @ W1[1536:1556,:] ----------
__global__ __launch_bounds__(256) void k_p4(const float* __restrict__ wwe,
                                            const float* __restrict__ W1,
                                            float* __restrict__ P4) {
    int o = blockIdx.x * 256 + threadIdx.x;
    if (o >= 30 * FFNN) return;
    int wi = o / FFNN, j = o - wi * FFNN;
    float acc = 0.f;
    #pragma unroll
    for (int f = 0; f < FEAT; ++f) acc += wwe[wi * FEAT + f] * W1[(1536 + f) * FFNN + j];
    P4[o] = acc;
}

// ---------- split fp32 -> bf16 hi/lo ----------
__global__ __launch_bounds__(256) void k_split(const float* __restrict__ src,
                                               ushort* __restrict__ h,
                                               ushort* __restrict__ l, int n) {
    int i = blockIdx.x * 256 + threadIdx.x;
    if (i >= n) return;
    float v = src[i];
    ushort hi = f2b(v);
    float r = v - b2f(hi);
    h[i] = hi;
    l[i] = f2b(r);
}

// ---------- W1 slices: transpose + split -> W1T[z][1024 n][768 k] hi/lo ----------
__global__ void k_tw1(const float* __restrict__ W1,
                      ushort* __restrict__ TH, ushort* __restrict__ TL) {
    __shared__ float tile[32][33];
    int tx = threadIdx.x, ty = threadIdx.y;
    int k0 = blockIdx.x * 32, n0 = blockIdx.y * 32, z = blockIdx.z;
    int roff = (z == 0) ? 0 : (z == 1) ? 768 : 1556;
    #pragma unroll
    for (int i = 0; i < 4; ++i) {
        int kk = ty + i * 8;
        float v = (n0 + tx < FFNN) ? W1[(size_t)(roff + k0 + kk) * FFNN + n0 + tx] : 0.f;
        tile[kk][tx] = v;
    }
    __syncthreads();
    #pragma unroll
    for (int i = 0; i < 4; ++i) {
        int nn = ty + i * 8;
        float v = tile[tx][nn];
        ushort hi = f2b(v);
        float r = v - b2f(hi);
        size_t o = (size_t)z * 1024 * D + (size_t)(n0 + nn) * D + k0 + tx;
        TH[o] = hi;
        TL[o] = f2b(r);
    }
}

// ---------- W2: transpose + split -> W2T[1024 n][1000 k] hi/lo ----------
__global__ void k_tw2(const float* __restrict__ W2,
                      ushort* __restrict__ TH, ushort* __restrict__ TL) {
    __shared__ float tile[32][33];
    int tx = threadIdx.x, ty = threadIdx.y;
    int k0 = blockIdx.x * 32, n0 = blockIdx.y * 32;
    #pragma unroll
    for (int i = 0; i < 4; ++i) {
        int kk = ty + i * 8;
        float v = (k0 + kk < FFNN && n0 + tx < FFNN)
                    ? W2[(size_t)(k0 + kk) * FFNN + n0 + tx] : 0.f;
        tile[kk][tx] = v;
    }
    __syncthreads();
    #pragma unroll
    for (int i = 0; i < 4; ++i) {
        int nn = ty + i * 8;
        int k = k0 + tx;
        if (k < FFNN) {
            float v = tile[tx][nn];
            ushort hi = f2b(v);
            float r = v - b2f(hi);
            size_t o = (size_t)(n0 + nn) * FFNN + k;
            TH[o] = hi;
            TL[o] = f2b(r);
        }
    }
}

// ---------- MFMA GEMM: P[z] = doc @ W1slice  (split-bf16 3-term, 128x128 tile) ----------
__global__ __launch_bounds__(256) void k_gemmPm(const ushort* __restrict__ Ah_g,
                                                const ushort* __restrict__ Al_g,
                                                const ushort* __restrict__ Bh_g,
                                                const ushort* __restrict__ Bl_g,
                                                float* __restrict__ Pout) {
    __shared__ ushort Ah[128][40], Al[128][40], Bh[128][40], Bl[128][40];
    int tid = threadIdx.x;
    int row0 = blockIdx.y * 128, col0 = blockIdx.x * 128;
    size_t zoff = (size_t)blockIdx.z * 1024 * D;
    const ushort* Bh_z = Bh_g + zoff;
    const ushort* Bl_z = Bl_g + zoff;
    float* C = Pout + (size_t)blockIdx.z * NW * FFNN;
    int w = tid >> 6, l = tid & 63;
    int wr = w >> 1, wc = w & 1;
    int fr = l & 15, kb = l >> 4;
    f32x4 acc[4][4] = {};
    for (int kt = 0; kt < D; kt += 32) {
        #pragma unroll
        for (int i = 0; i < 2; ++i) {
            int cid = tid + i * 256;
            int r = cid >> 2, kc = cid & 3;
            int kg = kt + kc * 8;
            uint4 a0 = *(const uint4*)(Ah_g + (size_t)(row0 + r) * D + kg);
            uint4 a1 = *(const uint4*)(Al_g + (size_t)(row0 + r) * D + kg);
            uint4 b0 = *(const uint4*)(Bh_z + (size_t)(col0 + r) * D + kg);
            uint4 b1 = *(const uint4*)(Bl_z + (size_t)(col0 + r) * D + kg);
            *(uint4*)&Ah[r][kc * 8] = a0;
            *(uint4*)&Al[r][kc * 8] = a1;
            *(uint4*)&Bh[r][kc * 8] = b0;
            *(uint4*)&Bl[r][kc * 8] = b1;
        }
        __syncthreads();
        bf16x8 af[4], alf[4], bfr[4], blf[4];
        #pragma unroll
        for (int mt = 0; mt < 4; ++mt) {
            int r = wr * 64 + mt * 16 + fr;
            af[mt]  = *(const bf16x8*)&Ah[r][kb * 8];
            alf[mt] = *(const bf16x8*)&Al[r][kb * 8];
        }
        #pragma unroll
        for (int nt = 0; nt < 4; ++nt) {
            int c = wc * 64 + nt * 16 + fr;
            bfr[nt] = *(const bf16x8*)&Bh[c][kb * 8];
            blf[nt] = *(const bf16x8*)&Bl[c][kb * 8];
        }
        #pragma unroll
        for (int mt = 0; mt < 4; ++mt)
            #pragma unroll
            for (int nt = 0; nt < 4; ++nt) {
                acc[mt][nt] = MFMA16(af[mt], bfr[nt], acc[mt][nt], 0, 0, 0);
                acc[mt][nt] = MFMA16(af[mt], blf[nt], acc[mt][nt], 0, 0, 0);
                acc[mt][nt] = MFMA16(alf[mt], bfr[nt], acc[mt][nt], 0, 0, 0);
            }
        __syncthreads();
    }
    #pragma unroll
    for (int mt = 0; mt < 4; ++mt)
        #pragma unroll
        for (int nt = 0; nt < 4; ++nt)
            #pragma unroll
            for (int r = 0; r < 4; ++r) {
                int row = row0 + wr * 64 + mt * 16 + kb * 4 + r;
                int col = col0 + wc * 64 + nt * 16 + fr;
                if (col < FFNN) C[(size_t)row * FFNN + col] = acc[mt][nt][r];
            }
}

// ---------- MFMA GEMM2 fused: relu(H1@W2+b2).W3 -> PS  (split-bf16, 128x128) ----------
__global__ __launch_bounds__(256) void k_gemm2m(const ushort* __restrict__ Ah_g,
                                                const ushort* __restrict__ Al_g,
                                                const ushort* __restrict__ Bh_g,
                                                const ushort* __restrict__ Bl_g,
                                                const float* __restrict__ b2,
                                                const float* __restrict__ W3,
                                                float* __restrict__ PS) {
    __shared__ ushort Ah[128][40], Al[128][40], Bh[128][40], Bl[128][40];
    int tid = threadIdx.x;
    int row0 = blockIdx.y * 128, col0 = blockIdx.x * 128;
    int w = tid >> 6, l = tid & 63;
    int wr = w >> 1, wc = w & 1;
    int fr = l & 15, kb = l >> 4;
    f32x4 acc[4][4] = {};
    for (int kt = 0; kt < FFNN; kt += 32) {
        #pragma unroll
        for (int i = 0; i < 2; ++i) {
            int cid = tid + i * 256;
            int r = cid >> 2, kc = cid & 3;
            int kg = kt + kc * 8;
            bool v = (kg + 7) < FFNN;        // FFNN%8==0 -> chunk fully valid or not
            uint4 z = make_uint4(0, 0, 0, 0);
            uint4 a0 = v ? *(const uint4*)(Ah_g + (size_t)(row0 + r) * FFNN + kg) : z;
            uint4 a1 = v ? *(const uint4*)(Al_g + (size_t)(row0 + r) * FFNN + kg) : z;
            uint4 b0 = v ? *(const uint4*)(Bh_g + (size_t)(col0 + r) * FFNN + kg) : z;
            uint4 b1 = v ? *(const uint4*)(Bl_g + (size_t)(col0 + r) * FFNN + kg) : z;
            *(uint4*)&Ah[r][kc * 8] = a0;
            *(uint4*)&Al[r][kc * 8] = a1;
            *(uint4*)&Bh[r][kc * 8] = b0;
            *(uint4*)&Bl[r][kc * 8] = b1;
        }
        __syncthreads();
        bf16x8 af[4], alf[4], bfr[4], blf[4];
        #pragma unroll
        for (int mt = 0; mt < 4; ++mt) {
            int r = wr * 64 + mt * 16 + fr;
            af[mt]  = *(const bf16x8*)&Ah[r][kb * 8];
            alf[mt] = *(const bf16x8*)&Al[r][kb * 8];
        }
        #pragma unroll
        for (int nt = 0; nt < 4; ++nt) {
            int c = wc * 64 + nt * 16 + fr;
            bfr[nt] = *(const bf16x8*)&Bh[c][kb * 8];
            blf[nt] = *(const bf16x8*)&Bl[c][kb * 8];
        }
        #pragma unroll
        for (int mt = 0; mt < 4; ++mt)
            #pragma unroll
            for (int nt = 0; nt < 4; ++nt) {
                acc[mt][nt] = MFMA16(af[mt], bfr[nt], acc[mt][nt], 0, 0, 0);
                acc[mt][nt] = MFMA16(af[mt], blf[nt], acc[mt][nt], 0, 0, 0);
                acc[mt][nt] = MFMA16(alf[mt], bfr[nt], acc[mt][nt], 0, 0, 0);
            }
        __syncthreads();
    }
    // epilogue: relu(acc + b2) . W3, reduce across the 16 col-lanes
    float w3v[4], b2v[4];
    #pragma unroll
    for (int nt = 0; nt < 4; ++nt) {
        int col = col0 + wc * 64 + nt * 16 + fr;
        bool cv = col < FFNN;
        w3v[nt] = cv ? W3[col] : 0.f;
        b2v[nt] = cv ? b2[col] : 0.f;
    }
    #pragma unroll
    for (int mt = 0; mt < 4; ++mt) {
        #pragma unroll
        for (int r = 0; r < 4; ++r) {
            float p = 0.f;
            #pragma unroll
            for (int nt = 0; nt < 4; ++nt) {
                float v = fmaxf(acc[mt][nt][r] + b2v[nt], 0.f);
                p = fmaf(v, w3v[nt], p);
            }
            p += __shfl_xor(p, 1);
            p += __shfl_xor(p, 2);
            p += __shfl_xor(p, 4);
            p += __shfl_xor(p, 8);
            if (fr == 0) {
                int row = row0 + wr * 64 + mt * 16 + kb * 4 + r;
                PS[row * 16 + blockIdx.x * 2 + wc] = p;
            }
        }
    }
}

// ---------- attention weights per span ----------
__global__ __launch_bounds__(256) void k_attn(const float* __restrict__ hs,
                                              const int* __restrict__ starts,
                                              const int* __restrict__ ends,
                                              float* __restrict__ attn) {
    int s = blockIdx.x * 256 + threadIdx.x;
    if (s >= NS) return;
    int st = starts[s], en = ends[s];
    int width = en - st + 1;
    float v[MAXW];
    float mx = -3.0e38f;
    #pragma unroll
    for (int w = 0; w < MAXW; ++w) {
        int idx = st + w; if (idx > NW - 1) idx = NW - 1;
        float x = hs[idx];
        v[w] = (w < width) ? x : -3.0e38f;
        mx = fmaxf(mx, v[w]);
    }
    float sum = 0.f;
    #pragma unroll
    for (int w = 0; w < MAXW; ++w) { v[w] = expf(v[w] - mx); sum += v[w]; }
    float inv = 1.f / sum;
    #pragma unroll
    for (int w = 0; w < MAXW; ++w) attn[s * 32 + w] = v[w] * inv;
}

// ---------- h1 assembly: gather P rows + attended + bias + relu -> bf16 hi/lo ----------
__global__ __launch_bounds__(256) void k_h1(const float* __restrict__ P,
                                            const float* __restrict__ P4,
                                            const float* __restrict__ attn,
                                            const float* __restrict__ b1,
                                            const int* __restrict__ starts,
                                            const int* __restrict__ ends,
                                            ushort* __restrict__ H1h,
                                            ushort* __restrict__ H1l) {
    int s = blockIdx.x;
    int tid = threadIdx.x;
    if (tid >= 250) return;
    int st = starts[s], en = ends[s];
    int width = en - st + 1;
    const float4* P1r = (const float4*)(P + (size_t)st * FFNN);
    const float4* P2r = (const float4*)(P + (size_t)NW * FFNN + (size_t)en * FFNN);
    const float*  P3  = P + 2 * (size_t)NW * FFNN;
    const float4* P4r = (const float4*)(P4 + (size_t)(width - 1) * FFNN);
    const float4* b1v = (const float4*)b1;
    const float*  ar  = attn + s * 32;
    float4 a = P1r[tid], b = P2r[tid], c = P4r[tid], d = b1v[tid];
    float4 acc = {a.x + b.x + c.x + d.x,
                  a.y + b.y + c.y + d.y,
                  a.z + b.z + c.z + d.z,
                  a.w + b.w + c.w + d.w};
    for (int w = 0; w < width; ++w) {
        float aw = ar[w];
        float4 p3 = ((const float4*)(P3 + (size_t)(st + w) * FFNN))[tid];
        acc.x = fmaf(aw, p3.x, acc.x);
        acc.y = fmaf(aw, p3.y, acc.y);
        acc.z = fmaf(aw, p3.z, acc.z);
        acc.w = fmaf(aw, p3.w, acc.w);
    }
    float rv[4] = {fmaxf(acc.x, 0.f), fmaxf(acc.y, 0.f), fmaxf(acc.z, 0.f), fmaxf(acc.w, 0.f)};
    ushort4 hi, lo;
    ushort* hp = (ushort*)&hi;
    ushort* lp = (ushort*)&lo;
    #pragma unroll
    for (int j = 0; j < 4; ++j) {
        ushort h = f2b(rv[j]);
        float r = rv[j] - b2f(h);
        hp[j] = h;
        lp[j] = f2b(r);
    }
    *(ushort4*)(H1h + (size_t)s * FFNN + tid * 4) = hi;
    *(ushort4*)(H1l + (size_t)s * FFNN + tid * 4) = lo;
}

// ---------- final score: sum 16 partials + b3 ----------
__global__ __launch_bounds__(256) void k_score2(const float* __restrict__ PS,
                                                const float* __restrict__ b3,
                                                float* __restrict__ out) {
    int r = blockIdx.x * 256 + threadIdx.x;
    if (r >= NS) return;
    float s = 0.f;
    #pragma unroll
    for (int b = 0; b < 16; ++b) s += PS[r * 16 + b];
    out[r] = s + b3[0];
}

// ---------- exact descending argsort via pairwise rank ----------
__global__ __launch_bounds__(256) void k_rank(const float* __restrict__ scores,
                                              int* __restrict__ order) {
    __shared__ unsigned long long tile[256];
    int i = blockIdx.x * 256 + threadIdx.x;
    unsigned u = __float_as_uint(scores[i]);
    unsigned m = (u >> 31) ? ~u : (u | 0x80000000u);
    unsigned long long key = ((unsigned long long)(~m) << 32) | (unsigned)i;
    int rank = 0;
    for (int t = 0; t < NS / 256; ++t) {
        int j = t * 256 + threadIdx.x;
        unsigned uj = __float_as_uint(scores[j]);
        unsigned mj = (uj >> 31) ? ~uj : (uj | 0x80000000u);
        tile[threadIdx.x] = ((unsigned long long)(~mj) << 32) | (unsigned)j;
        __syncthreads();
        #pragma unroll 8
        for (int q = 0; q < 256; ++q) rank += (tile[q] < key);
        __syncthreads();
    }
    order[rank] = i;
}

// ---------- greedy crossing-suppression scan: chunk-parallel exact resolution ----------
__global__ __launch_bounds__(64) void k_scan(const int* __restrict__ order,
                                             const int* __restrict__ starts,
                                             const int* __restrict__ ends,
                                             int top, float* __restrict__ out_idx) {
    __shared__ int max_end[NW];
    __shared__ int min_start[NW];
    __shared__ int sel[512];
    __shared__ int selkey[512];
    int lane = threadIdx.x;
    unsigned long long lower = (1ull << lane) - 1ull;
    for (int p = lane; p < NW; p += 64) { max_end[p] = -1; min_start[p] = NW; }
    for (int r = lane; r < top; r += 64) sel[r] = -1;
    __syncthreads();
    int count = 0;
    int span = order[lane];
    int s = starts[span], e = ends[span];
    for (int c = 0; c < NS / 64; ++c) {
        int nspan = 0, ns = 0, ne = 0;
        if (c + 1 < NS / 64) {
            nspan = order[(c + 1) * 64 + lane];
            ns = starts[nspan]; ne = ends[nspan];
        }
        int w = e - s;
        int bad = 0;
        for (int k = 0; k < w; ++k)
            bad |= (max_end[s + 1 + k] > e) | (min_start[s + k] < s);
        int g = max_end[s];
        bool gdup = (g == e), ggt = (g > e);
        unsigned long long M = __ballot(!bad);
        if (M) {
            unsigned long long conf = 0, eqm = 0, gtm = 0;
            unsigned long long t = M;
            while (t) {
                int i = __builtin_ctzll(t); t &= t - 1;
                int si = __builtin_amdgcn_readlane(s, i);
                int ei = __builtin_amdgcn_readlane(e, i);
                unsigned long long bit = 1ull << i;
                if (((si > s) & (si <= e) & (ei > e)) |
                    ((ei >= s) & (ei < e) & (si < s))) conf |= bit;
                if (si == s) { if (ei == e) eqm |= bit; else if (ei > e) gtm |= bit; }
            }
            unsigned long long pending = M, committed = 0;
            while (pending) {
                bool mine = (pending >> lane) & 1;
                unsigned long long relv = (conf | eqm | gtm) & lower;
                bool ready = mine && ((pending & relv) == 0ull);
                unsigned long long cb = committed & lower;
                bool rej = (cb & conf) != 0ull;
                bool gt_any = ggt || ((cb & gtm) != 0ull);
                bool eq_any = gdup || ((cb & eqm) != 0ull);
                bool acc_now = ready && !rej && !(eq_any && !gt_any);
                committed |= __ballot(acc_now);
                pending &= ~__ballot(ready);
            }
            int allowed = top - count;
            while (__popcll(committed) > allowed)
                committed &= ~(1ull << (63 - __builtin_clzll(committed)));
            if ((committed >> lane) & 1) {
                atomicMax(&max_end[s], e);
                atomicMin(&min_start[e], s);
                int pos = count + __popcll(committed & lower);
                sel[pos] = span;
            }
            count += __popcll(committed);
        }
        __syncthreads();
        if (count >= top) break;
        span = nspan; s = ns; e = ne;
    }
    for (int r = lane; r < top; r += 64) {
        int sp = sel[r];
        selkey[r] = (sp >= 0) ? (starts[sp] * NW + ends[sp]) : (NW * NW);
    }
    __syncthreads();
    for (int r = lane; r < top; r += 64) {
        int kr = selkey[r];
        int rank = 0;
        for (int q = 0; q < top; ++q) {
            int kq = selkey[q];
            rank += (kq < kr) || (kq == kr && q < r);
        }
        out_idx[rank] = (float)sel[r];
    }
}

extern "C" void kernel_launch(void* const* d_in, const int* in_sizes, int n_in,
                              void* d_out, int out_size, void* d_ws, size_t ws_size,
                              hipStream_t stream) {
    const float* doc = (const float*)d_in[0];
    const float* wwe = (const float*)d_in[1];
    const float* wh  = (const float*)d_in[2];
    const float* bh  = (const float*)d_in[3];
    const float* W1  = (const float*)d_in[4];
    const float* b1  = (const float*)d_in[5];
    const float* W2  = (const float*)d_in[6];
    const float* b2  = (const float*)d_in[7];
    const float* W3  = (const float*)d_in[8];
    const float* b3  = (const float*)d_in[9];
    const int* starts = (const int*)d_in[10];
    const int* ends   = (const int*)d_in[11];
    int top = out_size - NS;                 // 409

    float* ws  = (float*)d_ws;
    float* P   = ws + O_P;
    float* P4  = ws + O_P4;
    float* HS  = ws + O_HS;
    float* ATT = ws + O_ATT;
    float* PS  = ws + O_PS;
    int*   ORD = (int*)(ws + O_ORD);
    float* H1R = ws + O_H1R;
    ushort* H1H = (ushort*)H1R;
    ushort* H1L = (ushort*)(H1R + 4096000);
    // phase-A aliases (dead once k_h1 runs)
    ushort* W1TH = (ushort*)H1R;
    ushort* W1TL = (ushort*)(H1R + 1179648);
    ushort* DOCH = (ushort*)(H1R + 2359296);
    ushort* DOCL = (ushort*)(H1R + 2752512);
    // phase-B alias over P (dead once k_h1 done)
    ushort* W2TH = (ushort*)ws;
    ushort* W2TL = (ushort*)(ws + 512000);
    float* outs = (float*)d_out;

    k_head<<<NW / 4, 256, 0, stream>>>(doc, wh, bh, HS);
    k_p4<<<(30 * FFNN + 255) / 256, 256, 0, stream>>>(wwe, W1, P4);

    k_split<<<(NW * D + 255) / 256, 256, 0, stream>>>(doc, DOCH, DOCL, NW * D);
    {
        dim3 g(24, 32, 3), b(32, 8);
        k_tw1<<<g, b, 0, stream>>>(W1, W1TH, W1TL);
    }
    {
        dim3 g(8, 8, 3);
        k_gemmPm<<<g, 256, 0, stream>>>(DOCH, DOCL, W1TH, W1TL, P);
    }

    k_attn<<<NS / 256, 256, 0, stream>>>(HS, starts, ends, ATT);
    k_h1<<<NS, 256, 0, stream>>>(P, P4, ATT, b1, starts, ends, H1H, H1L);

    {
        dim3 g(32, 32), b(32, 8);
        k_tw2<<<g, b, 0, stream>>>(W2, W2TH, W2TL);
    }
    {
        dim3 g(8, NS / 128);
        k_gemm2m<<<g, 256, 0, stream>>>(H1H, H1L, W2TH, W2TL, b2, W3, PS);
    }

    k_score2<<<NS / 256, 256, 0, stream>>>(PS, b3, outs);
    k_rank<<<NS / 256, 256, 0, stream>>>(outs, ORD);
    k_scan<<<1, 64, 0, stream>>>(ORD, starts, ends, top, outs + NS);
}

// Round 5
// 514.045 us; speedup vs baseline: 2.0284x; 1.0180x over previous
//
#include <hip/hip_runtime.h>
#include <hip/hip_bf16.h>
#include <stdint.h>

#define NW   1024
#define D    768
#define NS   8192
#define MAXW 30
#define FFNN 1000
#define FEAT 20

typedef __attribute__((ext_vector_type(8))) short bf16x8;
typedef __attribute__((ext_vector_type(4))) float f32x4;
#define MFMA16 __builtin_amdgcn_mfma_f32_16x16x32_bf16

// ws layout (float-slot offsets) — total 11,696,432 floats = 46.78 MB
#define O_P    0                          // 3*1024*1000 fp32 P1,P2,P3
#define O_P4   3072000                    // 30*1000
#define O_HS   3102000                    // 1024
#define O_ATT  3103024                    // 8192*32
#define O_PS   3365168                    // 8192*16
#define O_ORD  3496240                    // 8192 ints
#define O_H1R  3504432                    // 8,192,000 fl region: H1 hi/lo bf16

__device__ inline ushort f2b(float v) {
    __hip_bfloat16 b = __float2bfloat16(v);
    return *(ushort*)&b;
}
__device__ inline float b2f(ushort u) {
    __hip_bfloat16 b = *(__hip_bfloat16*)&u;
    return __bfloat162float(b);
}

// ---------- head scores ----------
__global__ __launch_bounds__(256) void k_head(const float* __restrict__ doc,
                                              const float* __restrict__ wh,
                                              const float* __restrict__ bh,
                                              float* __restrict__ hs) {
    int wid = threadIdx.x >> 6, lane = threadIdx.x & 63;
    int word = blockIdx.x * 4 + wid;
    const float* row = doc + word * D;
    float acc = 0.f;
    for (int d = lane; d < D; d += 64) acc += row[d] * wh[d];
    #pragma unroll
    for (int o = 32; o; o >>= 1) acc += __shfl_down(acc, o);
    if (lane == 0) hs[word] = acc + bh[0];
}

// ---------- P4 = w_width_emb @ W1[1536:1556,:] ----------
__global__ __launch_bounds__(256) void k_p4(const float* __restrict__ wwe,
                                            const float* __restrict__ W1,
                                            float* __restrict__ P4) {
    int o = blockIdx.x * 256 + threadIdx.x;
    if (o >= 30 * FFNN) return;
    int wi = o / FFNN, j = o - wi * FFNN;
    float acc = 0.f;
    #pragma unroll
    for (int f = 0; f < FEAT; ++f) acc += wwe[wi * FEAT + f] * W1[(1536 + f) * FFNN + j];
    P4[o] = acc;
}

// ---------- split fp32 -> bf16 hi/lo ----------
__global__ __launch_bounds__(256) void k_split(const float* __restrict__ src,
                                               ushort* __restrict__ h,
                                               ushort* __restrict__ l, int n) {
    int i = blockIdx.x * 256 + threadIdx.x;
    if (i >= n) return;
    float v = src[i];
    ushort hi = f2b(v);
    float r = v - b2f(hi);
    h[i] = hi;
    l[i] = f2b(r);
}

// ---------- W1 slices: transpose + split -> W1T[z][1024 n][768 k] hi/lo ----------
__global__ void k_tw1(const float* __restrict__ W1,
                      ushort* __restrict__ TH, ushort* __restrict__ TL) {
    __shared__ float tile[32][33];
    int tx = threadIdx.x, ty = threadIdx.y;
    int k0 = blockIdx.x * 32, n0 = blockIdx.y * 32, z = blockIdx.z;
    int roff = (z == 0) ? 0 : (z == 1) ? 768 : 1556;
    #pragma unroll
    for (int i = 0; i < 4; ++i) {
        int kk = ty + i * 8;
        float v = (n0 + tx < FFNN) ? W1[(size_t)(roff + k0 + kk) * FFNN + n0 + tx] : 0.f;
        tile[kk][tx] = v;
    }
    __syncthreads();
    #pragma unroll
    for (int i = 0; i < 4; ++i) {
        int nn = ty + i * 8;
        float v = tile[tx][nn];
        ushort hi = f2b(v);
        float r = v - b2f(hi);
        size_t o = (size_t)z * 1024 * D + (size_t)(n0 + nn) * D + k0 + tx;
        TH[o] = hi;
        TL[o] = f2b(r);
    }
}

// ---------- W2: transpose + split -> W2T[1024 n][1000 k] hi/lo ----------
__global__ void k_tw2(const float* __restrict__ W2,
                      ushort* __restrict__ TH, ushort* __restrict__ TL) {
    __shared__ float tile[32][33];
    int tx = threadIdx.x, ty = threadIdx.y;
    int k0 = blockIdx.x * 32, n0 = blockIdx.y * 32;
    #pragma unroll
    for (int i = 0; i < 4; ++i) {
        int kk = ty + i * 8;
        float v = (k0 + kk < FFNN && n0 + tx < FFNN)
                    ? W2[(size_t)(k0 + kk) * FFNN + n0 + tx] : 0.f;
        tile[kk][tx] = v;
    }
    __syncthreads();
    #pragma unroll
    for (int i = 0; i < 4; ++i) {
        int nn = ty + i * 8;
        int k = k0 + tx;
        if (k < FFNN) {
            float v = tile[tx][nn];
            ushort hi = f2b(v);
            float r = v - b2f(hi);
            size_t o = (size_t)(n0 + nn) * FFNN + k;
            TH[o] = hi;
            TL[o] = f2b(r);
        }
    }
}

// ---------- MFMA GEMM: P[z] = doc @ W1slice  (split-bf16 3-term, 128x128 tile) ----------
__global__ __launch_bounds__(256) void k_gemmPm(const ushort* __restrict__ Ah_g,
                                                const ushort* __restrict__ Al_g,
                                                const ushort* __restrict__ Bh_g,
                                                const ushort* __restrict__ Bl_g,
                                                float* __restrict__ Pout) {
    __shared__ ushort Ah[128][40], Al[128][40], Bh[128][40], Bl[128][40];
    int tid = threadIdx.x;
    int row0 = blockIdx.y * 128, col0 = blockIdx.x * 128;
    size_t zoff = (size_t)blockIdx.z * 1024 * D;
    const ushort* Bh_z = Bh_g + zoff;
    const ushort* Bl_z = Bl_g + zoff;
    float* C = Pout + (size_t)blockIdx.z * NW * FFNN;
    int w = tid >> 6, l = tid & 63;
    int wr = w >> 1, wc = w & 1;
    int fr = l & 15, kb = l >> 4;
    f32x4 acc[4][4] = {};
    for (int kt = 0; kt < D; kt += 32) {
        #pragma unroll
        for (int i = 0; i < 2; ++i) {
            int cid = tid + i * 256;
            int r = cid >> 2, kc = cid & 3;
            int kg = kt + kc * 8;
            uint4 a0 = *(const uint4*)(Ah_g + (size_t)(row0 + r) * D + kg);
            uint4 a1 = *(const uint4*)(Al_g + (size_t)(row0 + r) * D + kg);
            uint4 b0 = *(const uint4*)(Bh_z + (size_t)(col0 + r) * D + kg);
            uint4 b1 = *(const uint4*)(Bl_z + (size_t)(col0 + r) * D + kg);
            *(uint4*)&Ah[r][kc * 8] = a0;
            *(uint4*)&Al[r][kc * 8] = a1;
            *(uint4*)&Bh[r][kc * 8] = b0;
            *(uint4*)&Bl[r][kc * 8] = b1;
        }
        __syncthreads();
        bf16x8 af[4], alf[4], bfr[4], blf[4];
        #pragma unroll
        for (int mt = 0; mt < 4; ++mt) {
            int r = wr * 64 + mt * 16 + fr;
            af[mt]  = *(const bf16x8*)&Ah[r][kb * 8];
            alf[mt] = *(const bf16x8*)&Al[r][kb * 8];
        }
        #pragma unroll
        for (int nt = 0; nt < 4; ++nt) {
            int c = wc * 64 + nt * 16 + fr;
            bfr[nt] = *(const bf16x8*)&Bh[c][kb * 8];
            blf[nt] = *(const bf16x8*)&Bl[c][kb * 8];
        }
        #pragma unroll
        for (int mt = 0; mt < 4; ++mt)
            #pragma unroll
            for (int nt = 0; nt < 4; ++nt) {
                acc[mt][nt] = MFMA16(af[mt], bfr[nt], acc[mt][nt], 0, 0, 0);
                acc[mt][nt] = MFMA16(af[mt], blf[nt], acc[mt][nt], 0, 0, 0);
                acc[mt][nt] = MFMA16(alf[mt], bfr[nt], acc[mt][nt], 0, 0, 0);
            }
        __syncthreads();
    }
    #pragma unroll
    for (int mt = 0; mt < 4; ++mt)
        #pragma unroll
        for (int nt = 0; nt < 4; ++nt)
            #pragma unroll
            for (int r = 0; r < 4; ++r) {
                int row = row0 + wr * 64 + mt * 16 + kb * 4 + r;
                int col = col0 + wc * 64 + nt * 16 + fr;
                if (col < FFNN) C[(size_t)row * FFNN + col] = acc[mt][nt][r];
            }
}

// ---------- MFMA GEMM2 fused: relu(H1@W2+b2).W3 -> PS  (split-bf16, 128x128) ----------
__global__ __launch_bounds__(256) void k_gemm2m(const ushort* __restrict__ Ah_g,
                                                const ushort* __restrict__ Al_g,
                                                const ushort* __restrict__ Bh_g,
                                                const ushort* __restrict__ Bl_g,
                                                const float* __restrict__ b2,
                                                const float* __restrict__ W3,
                                                float* __restrict__ PS) {
    __shared__ ushort Ah[128][40], Al[128][40], Bh[128][40], Bl[128][40];
    int tid = threadIdx.x;
    int row0 = blockIdx.y * 128, col0 = blockIdx.x * 128;
    int w = tid >> 6, l = tid & 63;
    int wr = w >> 1, wc = w & 1;
    int fr = l & 15, kb = l >> 4;
    f32x4 acc[4][4] = {};
    for (int kt = 0; kt < FFNN; kt += 32) {
        #pragma unroll
        for (int i = 0; i < 2; ++i) {
            int cid = tid + i * 256;
            int r = cid >> 2, kc = cid & 3;
            int kg = kt + kc * 8;
            bool v = (kg + 7) < FFNN;
            uint4 z = make_uint4(0, 0, 0, 0);
            uint4 a0 = v ? *(const uint4*)(Ah_g + (size_t)(row0 + r) * FFNN + kg) : z;
            uint4 a1 = v ? *(const uint4*)(Al_g + (size_t)(row0 + r) * FFNN + kg) : z;
            uint4 b0 = v ? *(const uint4*)(Bh_g + (size_t)(col0 + r) * FFNN + kg) : z;
            uint4 b1 = v ? *(const uint4*)(Bl_g + (size_t)(col0 + r) * FFNN + kg) : z;
            *(uint4*)&Ah[r][kc * 8] = a0;
            *(uint4*)&Al[r][kc * 8] = a1;
            *(uint4*)&Bh[r][kc * 8] = b0;
            *(uint4*)&Bl[r][kc * 8] = b1;
        }
        __syncthreads();
        bf16x8 af[4], alf[4], bfr[4], blf[4];
        #pragma unroll
        for (int mt = 0; mt < 4; ++mt) {
            int r = wr * 64 + mt * 16 + fr;
            af[mt]  = *(const bf16x8*)&Ah[r][kb * 8];
            alf[mt] = *(const bf16x8*)&Al[r][kb * 8];
        }
        #pragma unroll
        for (int nt = 0; nt < 4; ++nt) {
            int c = wc * 64 + nt * 16 + fr;
            bfr[nt] = *(const bf16x8*)&Bh[c][kb * 8];
            blf[nt] = *(const bf16x8*)&Bl[c][kb * 8];
        }
        #pragma unroll
        for (int mt = 0; mt < 4; ++mt)
            #pragma unroll
            for (int nt = 0; nt < 4; ++nt) {
                acc[mt][nt] = MFMA16(af[mt], bfr[nt], acc[mt][nt], 0, 0, 0);
                acc[mt][nt] = MFMA16(af[mt], blf[nt], acc[mt][nt], 0, 0, 0);
                acc[mt][nt] = MFMA16(alf[mt], bfr[nt], acc[mt][nt], 0, 0, 0);
            }
        __syncthreads();
    }
    float w3v[4], b2v[4];
    #pragma unroll
    for (int nt = 0; nt < 4; ++nt) {
        int col = col0 + wc * 64 + nt * 16 + fr;
        bool cv = col < FFNN;
        w3v[nt] = cv ? W3[col] : 0.f;
        b2v[nt] = cv ? b2[col] : 0.f;
    }
    #pragma unroll
    for (int mt = 0; mt < 4; ++mt) {
        #pragma unroll
        for (int r = 0; r < 4; ++r) {
            float p = 0.f;
            #pragma unroll
            for (int nt = 0; nt < 4; ++nt) {
                float v = fmaxf(acc[mt][nt][r] + b2v[nt], 0.f);
                p = fmaf(v, w3v[nt], p);
            }
            p += __shfl_xor(p, 1);
            p += __shfl_xor(p, 2);
            p += __shfl_xor(p, 4);
            p += __shfl_xor(p, 8);
            if (fr == 0) {
                int row = row0 + wr * 64 + mt * 16 + kb * 4 + r;
                PS[row * 16 + blockIdx.x * 2 + wc] = p;
            }
        }
    }
}

// ---------- attention weights per span ----------
__global__ __launch_bounds__(256) void k_attn(const float* __restrict__ hs,
                                              const int* __restrict__ starts,
                                              const int* __restrict__ ends,
                                              float* __restrict__ attn) {
    int s = blockIdx.x * 256 + threadIdx.x;
    if (s >= NS) return;
    int st = starts[s], en = ends[s];
    int width = en - st + 1;
    float v[MAXW];
    float mx = -3.0e38f;
    #pragma unroll
    for (int w = 0; w < MAXW; ++w) {
        int idx = st + w; if (idx > NW - 1) idx = NW - 1;
        float x = hs[idx];
        v[w] = (w < width) ? x : -3.0e38f;
        mx = fmaxf(mx, v[w]);
    }
    float sum = 0.f;
    #pragma unroll
    for (int w = 0; w < MAXW; ++w) { v[w] = expf(v[w] - mx); sum += v[w]; }
    float inv = 1.f / sum;
    #pragma unroll
    for (int w = 0; w < MAXW; ++w) attn[s * 32 + w] = v[w] * inv;
}

// ---------- h1 assembly: gather P rows + attended + bias + relu -> bf16 hi/lo ----------
__global__ __launch_bounds__(256) void k_h1(const float* __restrict__ P,
                                            const float* __restrict__ P4,
                                            const float* __restrict__ attn,
                                            const float* __restrict__ b1,
                                            const int* __restrict__ starts,
                                            const int* __restrict__ ends,
                                            ushort* __restrict__ H1h,
                                            ushort* __restrict__ H1l) {
    int s = blockIdx.x;
    int tid = threadIdx.x;
    if (tid >= 250) return;
    int st = starts[s], en = ends[s];
    int width = en - st + 1;
    const float4* P1r = (const float4*)(P + (size_t)st * FFNN);
    const float4* P2r = (const float4*)(P + (size_t)NW * FFNN + (size_t)en * FFNN);
    const float*  P3  = P + 2 * (size_t)NW * FFNN;
    const float4* P4r = (const float4*)(P4 + (size_t)(width - 1) * FFNN);
    const float4* b1v = (const float4*)b1;
    const float*  ar  = attn + s * 32;
    float4 a = P1r[tid], b = P2r[tid], c = P4r[tid], d = b1v[tid];
    float4 acc = {a.x + b.x + c.x + d.x,
                  a.y + b.y + c.y + d.y,
                  a.z + b.z + c.z + d.z,
                  a.w + b.w + c.w + d.w};
    for (int w = 0; w < width; ++w) {
        float aw = ar[w];
        float4 p3 = ((const float4*)(P3 + (size_t)(st + w) * FFNN))[tid];
        acc.x = fmaf(aw, p3.x, acc.x);
        acc.y = fmaf(aw, p3.y, acc.y);
        acc.z = fmaf(aw, p3.z, acc.z);
        acc.w = fmaf(aw, p3.w, acc.w);
    }
    float rv[4] = {fmaxf(acc.x, 0.f), fmaxf(acc.y, 0.f), fmaxf(acc.z, 0.f), fmaxf(acc.w, 0.f)};
    ushort4 hi, lo;
    ushort* hp = (ushort*)&hi;
    ushort* lp = (ushort*)&lo;
    #pragma unroll
    for (int j = 0; j < 4; ++j) {
        ushort h = f2b(rv[j]);
        float r = rv[j] - b2f(h);
        hp[j] = h;
        lp[j] = f2b(r);
    }
    *(ushort4*)(H1h + (size_t)s * FFNN + tid * 4) = hi;
    *(ushort4*)(H1l + (size_t)s * FFNN + tid * 4) = lo;
}

// ---------- final score: sum 16 partials + b3 ----------
__global__ __launch_bounds__(256) void k_score2(const float* __restrict__ PS,
                                                const float* __restrict__ b3,
                                                float* __restrict__ out) {
    int r = blockIdx.x * 256 + threadIdx.x;
    if (r >= NS) return;
    float s = 0.f;
    #pragma unroll
    for (int b = 0; b < 16; ++b) s += PS[r * 16 + b];
    out[r] = s + b3[0];
}

// ---------- exact descending argsort via pairwise rank ----------
__global__ __launch_bounds__(256) void k_rank(const float* __restrict__ scores,
                                              int* __restrict__ order) {
    __shared__ unsigned long long tile[256];
    int i = blockIdx.x * 256 + threadIdx.x;
    unsigned u = __float_as_uint(scores[i]);
    unsigned m = (u >> 31) ? ~u : (u | 0x80000000u);
    unsigned long long key = ((unsigned long long)(~m) << 32) | (unsigned)i;
    int rank = 0;
    for (int t = 0; t < NS / 256; ++t) {
        int j = t * 256 + threadIdx.x;
        unsigned uj = __float_as_uint(scores[j]);
        unsigned mj = (uj >> 31) ? ~uj : (uj | 0x80000000u);
        tile[threadIdx.x] = ((unsigned long long)(~mj) << 32) | (unsigned)j;
        __syncthreads();
        #pragma unroll 8
        for (int q = 0; q < 256; ++q) rank += (tile[q] < key);
        __syncthreads();
    }
    order[rank] = i;
}

// ---------- greedy crossing-suppression scan: chunk-parallel exact resolution ----------
// Cross-check fully unrolled (fixed 29 trips, masked) -> independent LDS loads
// that pipeline instead of a serial latency chain.
__global__ __launch_bounds__(64) void k_scan(const int* __restrict__ order,
                                             const int* __restrict__ starts,
                                             const int* __restrict__ ends,
                                             int top, float* __restrict__ out_idx) {
    __shared__ int max_end[NW];
    __shared__ int min_start[NW];
    __shared__ int sel[512];
    __shared__ int selkey[512];
    int lane = threadIdx.x;
    unsigned long long lower = (1ull << lane) - 1ull;
    for (int p = lane; p < NW; p += 64) { max_end[p] = -1; min_start[p] = NW; }
    for (int r = lane; r < top; r += 64) sel[r] = -1;
    __syncthreads();
    int count = 0;
    int span = order[lane];
    int s = starts[span], e = ends[span];
    for (int c = 0; c < NS / 64; ++c) {
        int nspan = 0, ns = 0, ne = 0;
        if (c + 1 < NS / 64) {
            nspan = order[(c + 1) * 64 + lane];
            ns = starts[nspan]; ne = ends[nspan];
        }
        int w = e - s;
        // fully-unrolled masked cross check: 58 independent LDS loads, pipelined
        int bad = 0;
        #pragma unroll
        for (int k = 0; k < MAXW - 1; ++k) {
            int i1 = min(s + 1 + k, NW - 1);   // clamped; masked lanes only
            int i2 = min(s + k, NW - 1);
            int hit = (max_end[i1] > e) | (min_start[i2] < s);
            bad |= (k < w) ? hit : 0;
        }
        int g = max_end[s];
        bool gdup = (g == e), ggt = (g > e);
        unsigned long long M = __ballot(!bad);
        if (M) {
            unsigned long long conf = 0, eqm = 0, gtm = 0;
            unsigned long long t = M;
            while (t) {
                int i = __builtin_ctzll(t); t &= t - 1;
                int si = __builtin_amdgcn_readlane(s, i);
                int ei = __builtin_amdgcn_readlane(e, i);
                unsigned long long bit = 1ull << i;
                if (((si > s) & (si <= e) & (ei > e)) |
                    ((ei >= s) & (ei < e) & (si < s))) conf |= bit;
                if (si == s) { if (ei == e) eqm |= bit; else if (ei > e) gtm |= bit; }
            }
            unsigned long long pending = M, committed = 0;
            while (pending) {
                bool mine = (pending >> lane) & 1;
                unsigned long long relv = (conf | eqm | gtm) & lower;
                bool ready = mine && ((pending & relv) == 0ull);
                unsigned long long cb = committed & lower;
                bool rej = (cb & conf) != 0ull;
                bool gt_any = ggt || ((cb & gtm) != 0ull);
                bool eq_any = gdup || ((cb & eqm) != 0ull);
                bool acc_now = ready && !rej && !(eq_any && !gt_any);
                committed |= __ballot(acc_now);
                pending &= ~__ballot(ready);
            }
            int allowed = top - count;
            while (__popcll(committed) > allowed)
                committed &= ~(1ull << (63 - __builtin_clzll(committed)));
            if ((committed >> lane) & 1) {
                atomicMax(&max_end[s], e);
                atomicMin(&min_start[e], s);
                int pos = count + __popcll(committed & lower);
                sel[pos] = span;
            }
            count += __popcll(committed);
        }
        __syncthreads();
        if (count >= top) break;
        span = nspan; s = ns; e = ne;
    }
    for (int r = lane; r < top; r += 64) {
        int sp = sel[r];
        selkey[r] = (sp >= 0) ? (starts[sp] * NW + ends[sp]) : (NW * NW);
    }
    __syncthreads();
    for (int r = lane; r < top; r += 64) {
        int kr = selkey[r];
        int rank = 0;
        for (int q = 0; q < top; ++q) {
            int kq = selkey[q];
            rank += (kq < kr) || (kq == kr && q < r);
        }
        out_idx[rank] = (float)sel[r];
    }
}

extern "C" void kernel_launch(void* const* d_in, const int* in_sizes, int n_in,
                              void* d_out, int out_size, void* d_ws, size_t ws_size,
                              hipStream_t stream) {
    const float* doc = (const float*)d_in[0];
    const float* wwe = (const float*)d_in[1];
    const float* wh  = (const float*)d_in[2];
    const float* bh  = (const float*)d_in[3];
    const float* W1  = (const float*)d_in[4];
    const float* b1  = (const float*)d_in[5];
    const float* W2  = (const float*)d_in[6];
    const float* b2  = (const float*)d_in[7];
    const float* W3  = (const float*)d_in[8];
    const float* b3  = (const float*)d_in[9];
    const int* starts = (const int*)d_in[10];
    const int* ends   = (const int*)d_in[11];
    int top = out_size - NS;                 // 409

    float* ws  = (float*)d_ws;
    float* P   = ws + O_P;
    float* P4  = ws + O_P4;
    float* HS  = ws + O_HS;
    float* ATT = ws + O_ATT;
    float* PS  = ws + O_PS;
    int*   ORD = (int*)(ws + O_ORD);
    float* H1R = ws + O_H1R;
    ushort* H1H = (ushort*)H1R;
    ushort* H1L = (ushort*)(H1R + 4096000);
    ushort* W1TH = (ushort*)H1R;
    ushort* W1TL = (ushort*)(H1R + 1179648);
    ushort* DOCH = (ushort*)(H1R + 2359296);
    ushort* DOCL = (ushort*)(H1R + 2752512);
    ushort* W2TH = (ushort*)ws;
    ushort* W2TL = (ushort*)(ws + 512000);
    float* outs = (float*)d_out;

    k_head<<<NW / 4, 256, 0, stream>>>(doc, wh, bh, HS);
    k_p4<<<(30 * FFNN + 255) / 256, 256, 0, stream>>>(wwe, W1, P4);

    k_split<<<(NW * D + 255) / 256, 256, 0, stream>>>(doc, DOCH, DOCL, NW * D);
    {
        dim3 g(24, 32, 3), b(32, 8);
        k_tw1<<<g, b, 0, stream>>>(W1, W1TH, W1TL);
    }
    {
        dim3 g(8, 8, 3);
        k_gemmPm<<<g, 256, 0, stream>>>(DOCH, DOCL, W1TH, W1TL, P);
    }

    k_attn<<<NS / 256, 256, 0, stream>>>(HS, starts, ends, ATT);
    k_h1<<<NS, 256, 0, stream>>>(P, P4, ATT, b1, starts, ends, H1H, H1L);

    {
        dim3 g(32, 32), b(32, 8);
        k_tw2<<<g, b, 0, stream>>>(W2, W2TH, W2TL);
    }
    {
        dim3 g(8, NS / 128);
        k_gemm2m<<<g, 256, 0, stream>>>(H1H, H1L, W2TH, W2TL, b2, W3, PS);
    }

    k_score2<<<NS / 256, 256, 0, stream>>>(PS, b3, outs);
    k_rank<<<NS / 256, 256, 0, stream>>>(outs, ORD);
    k_scan<<<1, 64, 0, stream>>>(ORD, starts, ends, top, outs + NS);
}